// Round 5
// baseline (994.410 us; speedup 1.0000x reference)
//
#include <hip/hip_runtime.h>
#include <hip/hip_bf16.h>
#include <math.h>

#define N_ATOMS 2048
#define E_EDGES 65536
#define B_BATCH 8
#define H_DIM 128
#define G_DIM 50
#define F_DIM 64
#define S_DIM 16
#define MH_DIM 32
#define K_TOP 512
#define L_LAYERS 2
#define EPB 64          // edges per block in k_edge/k_aggs (8 per wave, 8 waves)

static constexpr float STEP   = 10.0f / 49.0f;          // OFFSET spacing
static constexpr float COEFF  = -12.005f;               // -0.5/STEP^2
static constexpr float PI10   = 0.31415926535897931f;   // pi/CUTOFF
static constexpr float LN2    = 0.69314718055994531f;
static constexpr float LAMBDA = 0.002f;

#define DEV static __device__ __forceinline__

DEV float ssp_f(float x) { return fmaxf(x, 0.f) + log1pf(expf(-fabsf(x))) - LN2; }
DEV float ccut_f(float d) { return 0.5f * (cosf(d * PI10) + 1.f); }
DEV float sigm_f(float x) { return 1.f / (1.f + expf(-x)); }

// ---------------- dtype detect: bf16-interp of fp32 data shows huge/NaN values ----------------
__global__ __launch_bounds__(256) void k_detect(const unsigned short* raw, int n, int* flag) {
    __shared__ int any;
    if (threadIdx.x == 0) any = 0;
    __syncthreads();
    for (int i = threadIdx.x; i < n; i += 256) {
        unsigned int bits = ((unsigned int)raw[i]) << 16;
        float f = __uint_as_float(bits);
        if (!(fabsf(f) <= 1e10f)) any = 1;   // catches NaN and huge => source is fp32
    }
    __syncthreads();
    if (threadIdx.x == 0) flag[0] = any;
}

// ---------------- fused convert of all float inputs -> fp32 workspace ----------------
struct ConvArgs {
    const void* p[25];
    int off[26];     // prefix offsets into dst; off[25] = total
};

__global__ __launch_bounds__(256) void k_convert_all(ConvArgs a, float* dst, const int* flag) {
    int i = blockIdx.x * 256 + threadIdx.x;
    int total = a.off[25];
    if (i >= total) return;
    int seg = 0;
    while (i >= a.off[seg + 1]) seg++;
    int k = i - a.off[seg];
    if (flag[0]) {
        dst[i] = ((const float*)a.p[seg])[k];
    } else {
        unsigned int bits = ((unsigned int)((const unsigned short*)a.p[seg])[k]) << 16;
        dst[i] = __uint_as_float(bits);
    }
}

// ---------------- embedding ----------------
__global__ __launch_bounds__(256) void k_embed(const int* atoms, const float* emb, float* h) {
    int i = blockIdx.x * 256 + threadIdx.x;     // N*H
    int n = i >> 7, c = i & 127;
    h[i] = emb[atoms[n] * H_DIM + c];
}

// ---------------- x = h @ cf1  (M x 128 @ 128 x 64) ----------------
__global__ __launch_bounds__(256) void k_x(const float* __restrict__ h, const float* __restrict__ cf1,
                                           float* __restrict__ x, int M) {
    int wave = threadIdx.x >> 6, lane = threadIdx.x & 63;
    int n = blockIdx.x * 4 + wave;
    if (n >= M) return;
    float acc = 0.f;
    for (int k = 0; k < H_DIM; k++) acc += h[n * H_DIM + k] * cf1[k * F_DIM + lane];
    x[n * F_DIM + lane] = acc;
}

// ---------------- edge filter + scatter into agg (atomic), 8 waves x 8 edges ----------------
__global__ __launch_bounds__(512) void k_edge(const float* pos, const int* src, const int* dst,
                                              const float* x,
                                              const float* mw1, const float* mb1,
                                              const float* mw2, const float* mb2,
                                              float* agg) {
    __shared__ float mw1s[G_DIM * F_DIM];
    __shared__ float mw2s[F_DIM * F_DIM];
    __shared__ float mb1s[F_DIM], mb2s[F_DIM];
    __shared__ float gb[8][G_DIM], tb[8][F_DIM];
    int t = threadIdx.x, wave = t >> 6, lane = t & 63;
    for (int i = t; i < G_DIM * F_DIM; i += 512) mw1s[i] = mw1[i];
    for (int i = t; i < F_DIM * F_DIM; i += 512) mw2s[i] = mw2[i];
    if (t < F_DIM) { mb1s[t] = mb1[t]; mb2s[t] = mb2[t]; }
    __syncthreads();
    int e0 = blockIdx.x * EPB + wave * (EPB / 8);
    for (int ee = 0; ee < EPB / 8; ee++) {
        int e = e0 + ee;
        int sI = src[e], dI = dst[e];
        float dx = pos[sI * 3 + 0] - pos[dI * 3 + 0];
        float dy = pos[sI * 3 + 1] - pos[dI * 3 + 1];
        float dz = pos[sI * 3 + 2] - pos[dI * 3 + 2];
        float d = sqrtf(dx * dx + dy * dy + dz * dz + 1e-12f);
        if (lane < G_DIM) { float u = d - lane * STEP; gb[wave][lane] = expf(COEFF * u * u); }
        // wave-lockstep: per-wave LDS buffers need no barrier
        float tv = mb1s[lane];
        for (int g = 0; g < G_DIM; g++) tv += gb[wave][g] * mw1s[g * F_DIM + lane];
        tv = ssp_f(tv);
        tb[wave][lane] = tv;
        float w = mb2s[lane];
        for (int k = 0; k < F_DIM; k++) w += tb[wave][k] * mw2s[k * F_DIM + lane];
        w *= ccut_f(d);
        atomicAdd(&agg[dI * F_DIM + lane], x[sI * F_DIM + lane] * w);
    }
}

// ---------------- out = base + ssp(agg@cf2w + cf2b) @ lw + lb ----------------
__global__ __launch_bounds__(256) void k_update(const float* __restrict__ agg, const float* __restrict__ base,
                                                const float* cf2w, const float* cf2b,
                                                const float* lw, const float* lb,
                                                float* out, int M) {
    __shared__ float tbuf[4][H_DIM];
    int wave = threadIdx.x >> 6, lane = threadIdx.x & 63;
    int n = blockIdx.x * 4 + wave;
    float t0 = cf2b[lane], t1 = cf2b[lane + 64];
    if (n < M) {
        for (int f = 0; f < F_DIM; f++) {
            float a = agg[n * F_DIM + f];
            t0 += a * cf2w[f * H_DIM + lane];
            t1 += a * cf2w[f * H_DIM + lane + 64];
        }
    }
    tbuf[wave][lane] = ssp_f(t0);
    tbuf[wave][lane + 64] = ssp_f(t1);
    __syncthreads();
    if (n < M) {
        float o0 = lb[lane], o1 = lb[lane + 64];
        for (int k = 0; k < H_DIM; k++) {
            float tv = tbuf[wave][k];
            o0 += tv * lw[k * H_DIM + lane];
            o1 += tv * lw[k * H_DIM + lane + 64];
        }
        out[n * H_DIM + lane]      = base[n * H_DIM + lane] + o0;
        out[n * H_DIM + lane + 64] = base[n * H_DIM + lane + 64] + o1;
    }
}

// ---------------- node scores ----------------
__global__ __launch_bounds__(256) void k_scores(const float* h_local,
                                                const float* msw1, const float* msb1,
                                                const float* msw2, const float* msb2,
                                                float* scores) {
    int n = blockIdx.x * 256 + threadIdx.x;
    if (n >= N_ATOMS) return;
    float hs[S_DIM];
    for (int s = 0; s < S_DIM; s++) hs[s] = h_local[n * H_DIM + s];
    float sc = msb2[0];
    for (int j = 0; j < MH_DIM; j++) {
        float v = msb1[j];
        for (int s = 0; s < S_DIM; s++) v += hs[s] * msw1[s * MH_DIM + j];
        sc += fmaxf(v, 0.f) * msw2[j];
    }
    scores[n] = sc;
}

// ---------------- exact rank (ties -> lower index wins, matching top_k) ----------------
__global__ __launch_bounds__(256) void k_rank(const float* scores, int* rank) {
    __shared__ float s[N_ATOMS];
    for (int i = threadIdx.x; i < N_ATOMS; i += 256) s[i] = scores[i];
    __syncthreads();
    int i = blockIdx.x * 256 + threadIdx.x;
    float si = s[i];
    int r = 0;
    for (int j = 0; j < N_ATOMS; j++) {
        float sj = s[j];
        r += (sj > si) || (sj == si && j < i);
    }
    rank[i] = r;
}

// ---------------- selection, prefix, midx, m ----------------
__global__ __launch_bounds__(1024) void k_select(const float* scores, const int* rank,
                                                 int* is_m, int* invg, int* midx, float* m) {
    __shared__ int flag[N_ATOMS];
    __shared__ int bufA[N_ATOMS], bufB[N_ATOMS];
    __shared__ float kth;
    int t = threadIdx.x;
    for (int i = t; i < N_ATOMS; i += 1024) {
        int f = rank[i] < K_TOP;
        flag[i] = f;
        bufA[i] = f;
        if (rank[i] == K_TOP - 1) kth = scores[i];
    }
    __syncthreads();
    int* in = bufA;
    int* out = bufB;
    for (int d = 1; d < N_ATOMS; d <<= 1) {
        for (int i = t; i < N_ATOMS; i += 1024) out[i] = in[i] + (i >= d ? in[i - d] : 0);
        __syncthreads();
        int* tmp = in; in = out; out = tmp;
    }
    float kv = kth;
    for (int i = t; i < N_ATOMS; i += 1024) {
        int f = flag[i];
        int pos = in[i] - f;   // exclusive prefix
        is_m[i] = f;
        invg[i] = f ? pos : 0;
        if (f) midx[pos] = i;
        m[i] = sigm_f(scores[i] - kv + 1e-6f);
    }
}

// ---------------- gather h_m / pos_m ----------------
__global__ __launch_bounds__(256) void k_gather(const int* midx, const float* h_local,
                                                const float* pos, float* h_m, float* pos_m) {
    int i = blockIdx.x * 256 + threadIdx.x;  // K*H
    int k = i >> 7, c = i & 127;
    int n = midx[k];
    h_m[i] = h_local[n * H_DIM + c];
    if (c < 3) pos_m[k * 3 + c] = pos[n * 3 + c];
}

// ---------------- adjacency among selected ----------------
__global__ __launch_bounds__(256) void k_adj(const int* src, const int* dst, const int* is_m,
                                             const int* invg, unsigned char* adj) {
    int e = blockIdx.x * 256 + threadIdx.x;
    int s = src[e], d = dst[e];
    if (is_m[s] && is_m[d]) adj[invg[s] * K_TOP + invg[d]] = 1;
}

// ---------------- q/k projections (S=16), 256-thread blocks ----------------
__global__ __launch_bounds__(256) void k_qk(const float* h_m, const float* wq,
                                            const float* wk, float* qm, float* km) {
    int gid = blockIdx.x * 256 + threadIdx.x;   // K*32
    int r = gid >> 5, t = gid & 31;
    const float* w = (t < 16) ? wq : wk;
    int c = t & 15;
    float acc = 0.f;
    for (int s = 0; s < S_DIM; s++) acc += h_m[r * H_DIM + s] * w[s * S_DIM + c];
    if (t < 16) qm[r * S_DIM + c] = acc; else km[r * S_DIM + c] = acc;
}

// ---------------- attention softmax -> Av mask ----------------
__global__ __launch_bounds__(256) void k_attn(const float* qm, const float* km,
                                              const unsigned char* adj, unsigned char* Av) {
    __shared__ float lrow[K_TOP];
    __shared__ float red[256];
    int i = blockIdx.x, t = threadIdx.x;
    float q[S_DIM];
    for (int s = 0; s < S_DIM; s++) q[s] = qm[i * S_DIM + s];
    for (int j = t; j < K_TOP; j += 256) {
        float acc = 0.f;
        for (int s = 0; s < S_DIM; s++) acc += q[s] * km[j * S_DIM + s];
        lrow[j] = acc * 0.25f;   // / sqrt(16)
    }
    __syncthreads();
    float mx = -1e30f;
    for (int j = t; j < K_TOP; j += 256) mx = fmaxf(mx, lrow[j]);
    red[t] = mx; __syncthreads();
    for (int o = 128; o > 0; o >>= 1) { if (t < o) red[t] = fmaxf(red[t], red[t + o]); __syncthreads(); }
    mx = red[0]; __syncthreads();
    float sum = 0.f;
    for (int j = t; j < K_TOP; j += 256) sum += expf(lrow[j] - mx);
    red[t] = sum; __syncthreads();
    for (int o = 128; o > 0; o >>= 1) { if (t < o) red[t] += red[t + o]; __syncthreads(); }
    float inv_s = 1.f / red[0];
    for (int j = t; j < K_TOP; j += 256) {
        float a = expf(lrow[j] - mx) * inv_s;
        Av[i * K_TOP + j] = (a > LAMBDA) && (!adj[i * K_TOP + j]) && (i != j);
    }
}

// ---------------- pairwise distances ----------------
__global__ __launch_bounds__(256) void k_dmat(const float* pos_m, float* dmat) {
    int idx = blockIdx.x * 256 + threadIdx.x;   // K*K
    int i = idx >> 9, j = idx & (K_TOP - 1);
    float dx = pos_m[i * 3 + 0] - pos_m[j * 3 + 0];
    float dy = pos_m[i * 3 + 1] - pos_m[j * 3 + 1];
    float dz = pos_m[i * 3 + 2] - pos_m[j * 3 + 2];
    dmat[idx] = sqrtf(dx * dx + dy * dy + dz * dz + 1e-12f);
}

// ---------------- hi = h_m@Wi, hj = h_m@Wj ----------------
__global__ __launch_bounds__(256) void k_hij(const float* h_m, const float* aw1,
                                             float* hi, float* hj) {
    int wave = threadIdx.x >> 6, lane = threadIdx.x & 63;
    int idx = blockIdx.x * 4 + wave;            // 0..1023
    int which = idx >> 9;
    int r = idx & (K_TOP - 1);
    const float* W = aw1 + which * H_DIM * H_DIM;
    float o0 = 0.f, o1 = 0.f;
    for (int k = 0; k < H_DIM; k++) {
        float hv = h_m[r * H_DIM + k];
        o0 += hv * W[k * H_DIM + lane];
        o1 += hv * W[k * H_DIM + lane + 64];
    }
    float* out = which ? hj : hi;
    out[r * H_DIM + lane] = o0;
    out[r * H_DIM + lane + 64] = o1;
}

// ---------------- per-row attention scores (split over j halves) ----------------
__global__ __launch_bounds__(512) void k_score(const float* hi, const float* hj,
                                               const float* aw1, const float* ab1,
                                               const float* aw2, const float* ab2,
                                               const float* dmat, const unsigned char* Av,
                                               float* sbuf) {
    __shared__ float Wd[G_DIM * H_DIM];
    __shared__ float his[H_DIM], ab1s[H_DIM], aw2s[H_DIM];
    __shared__ float gb[8][G_DIM];
    int i = blockIdx.x & (K_TOP - 1), half = blockIdx.x >> 9;
    int t = threadIdx.x, wave = t >> 6, lane = t & 63;
    const float* wd = aw1 + 2 * H_DIM * H_DIM;
    for (int idx = t; idx < G_DIM * H_DIM; idx += 512) Wd[idx] = wd[idx];
    if (t < H_DIM) { his[t] = hi[i * H_DIM + t]; ab1s[t] = ab1[t]; aw2s[t] = aw2[t]; }
    __syncthreads();
    float b2 = ab2[0];
    int jbase = half * (K_TOP / 2);
    for (int j = jbase + wave; j < jbase + K_TOP / 2; j += 8) {
        bool act = Av[i * K_TOP + j] != 0;
        float sc = -1e9f;
        if (act) {
            float dd = dmat[i * K_TOP + j];
            if (lane < G_DIM) { float u = dd - lane * STEP; gb[wave][lane] = expf(COEFF * u * u); }
            float v0 = his[lane] + hj[j * H_DIM + lane] + ab1s[lane];
            float v1 = his[lane + 64] + hj[j * H_DIM + lane + 64] + ab1s[lane + 64];
            for (int g = 0; g < G_DIM; g++) {
                float gv = gb[wave][g];
                v0 += gv * Wd[g * H_DIM + lane];
                v1 += gv * Wd[g * H_DIM + lane + 64];
            }
            float p = fmaxf(v0, 0.f) * aw2s[lane] + fmaxf(v1, 0.f) * aw2s[lane + 64];
            for (int o = 1; o < 64; o <<= 1) p += __shfl_xor(p, o);
            sc = p + b2;
        }
        if (lane == 0) sbuf[i * K_TOP + j] = sc;
    }
}

// ---------------- row softmax over sbuf -> decay ----------------
__global__ __launch_bounds__(256) void k_decay(const float* sbuf, float* decay) {
    __shared__ float srow[K_TOP];
    __shared__ float red[256];
    int i = blockIdx.x, t = threadIdx.x;
    for (int j = t; j < K_TOP; j += 256) srow[j] = sbuf[i * K_TOP + j];
    __syncthreads();
    float mx = -1e30f;
    for (int j = t; j < K_TOP; j += 256) mx = fmaxf(mx, srow[j]);
    red[t] = mx; __syncthreads();
    for (int o = 128; o > 0; o >>= 1) { if (t < o) red[t] = fmaxf(red[t], red[t + o]); __syncthreads(); }
    mx = red[0]; __syncthreads();
    float sum = 0.f;
    for (int j = t; j < K_TOP; j += 256) sum += (srow[j] > -5e8f) ? expf(srow[j] - mx) : 0.f;
    red[t] = sum; __syncthreads();
    for (int o = 128; o > 0; o >>= 1) { if (t < o) red[t] += red[t + o]; __syncthreads(); }
    float s_total = red[0];
    float inv_s = (s_total > 0.f) ? 1.f / s_total : 0.f;
    for (int j = t; j < K_TOP; j += 256)
        decay[i * K_TOP + j] = (srow[j] > -5e8f) ? expf(srow[j] - mx) * inv_s : 0.f;
}

// ---------------- agg_d: 8 waves, i-range split over 2 blocks, atomic merge ----------------
#define AGGD_SPLIT 2
__global__ __launch_bounds__(512) void k_aggd(const float* xm, const float* dmat, const float* decay,
                                              const unsigned char* Av,
                                              const float* mw1, const float* mb1,
                                              const float* mw2, const float* mb2,
                                              float* agg_m) {
    __shared__ float mw1s[G_DIM * F_DIM];
    __shared__ float mw2s[F_DIM * F_DIM];
    __shared__ float mb1s[F_DIM], mb2s[F_DIM];
    __shared__ float gb[8][G_DIM], tb[8][F_DIM];
    __shared__ float accs[8][F_DIM];
    int j = blockIdx.x & (K_TOP - 1), half = blockIdx.x >> 9;
    int t = threadIdx.x, wave = t >> 6, lane = t & 63;
    for (int i = t; i < G_DIM * F_DIM; i += 512) mw1s[i] = mw1[i];
    for (int i = t; i < F_DIM * F_DIM; i += 512) mw2s[i] = mw2[i];
    if (t < F_DIM) { mb1s[t] = mb1[t]; mb2s[t] = mb2[t]; }
    __syncthreads();
    float acc = 0.f;
    int ibase = half * (K_TOP / AGGD_SPLIT);
    for (int i = ibase + wave; i < ibase + K_TOP / AGGD_SPLIT; i += 8) {
        if (!Av[i * K_TOP + j]) continue;
        float dd = dmat[i * K_TOP + j];
        float dec = decay[i * K_TOP + j];
        if (lane < G_DIM) { float u = dd - lane * STEP; gb[wave][lane] = expf(COEFF * u * u) * dec; }
        float tv = mb1s[lane];
        for (int g = 0; g < G_DIM; g++) tv += gb[wave][g] * mw1s[g * F_DIM + lane];
        tv = ssp_f(tv);
        tb[wave][lane] = tv;
        float w = mb2s[lane];
        for (int k = 0; k < F_DIM; k++) w += tb[wave][k] * mw2s[k * F_DIM + lane];
        acc += xm[i * F_DIM + lane] * w * ccut_f(dd);
    }
    accs[wave][lane] = acc;
    __syncthreads();
    if (wave == 0) {
        float s = accs[0][lane] + accs[1][lane] + accs[2][lane] + accs[3][lane]
                + accs[4][lane] + accs[5][lane] + accs[6][lane] + accs[7][lane];
        atomicAdd(&agg_m[j * F_DIM + lane], s);
    }
}

// ---------------- valid-edge filter scatter into agg_m, 8 waves x 8 edges ----------------
__global__ __launch_bounds__(512) void k_aggs(const float* pos_m, const int* src, const int* dst,
                                              const int* is_m, const int* invg, const float* xm,
                                              const float* mw1, const float* mb1,
                                              const float* mw2, const float* mb2,
                                              float* agg_m) {
    __shared__ float mw1s[G_DIM * F_DIM];
    __shared__ float mw2s[F_DIM * F_DIM];
    __shared__ float mb1s[F_DIM], mb2s[F_DIM];
    __shared__ float gb[8][G_DIM], tb[8][F_DIM];
    int t = threadIdx.x, wave = t >> 6, lane = t & 63;
    for (int i = t; i < G_DIM * F_DIM; i += 512) mw1s[i] = mw1[i];
    for (int i = t; i < F_DIM * F_DIM; i += 512) mw2s[i] = mw2[i];
    if (t < F_DIM) { mb1s[t] = mb1[t]; mb2s[t] = mb2[t]; }
    __syncthreads();
    int e0 = blockIdx.x * EPB + wave * (EPB / 8);
    for (int ee = 0; ee < EPB / 8; ee++) {
        int e = e0 + ee;
        int s = src[e], dn = dst[e];
        bool valid = is_m[s] && is_m[dn];
        if (!valid) continue;
        int sm = invg[s];
        int dm = invg[dn];
        float dx = pos_m[sm * 3 + 0] - pos_m[dm * 3 + 0];
        float dy = pos_m[sm * 3 + 1] - pos_m[dm * 3 + 1];
        float dz = pos_m[sm * 3 + 2] - pos_m[dm * 3 + 2];
        float d = sqrtf(dx * dx + dy * dy + dz * dz + 1e-12f);
        if (lane < G_DIM) { float u = d - lane * STEP; gb[wave][lane] = expf(COEFF * u * u); }
        float tv = mb1s[lane];
        for (int g = 0; g < G_DIM; g++) tv += gb[wave][g] * mw1s[g * F_DIM + lane];
        tv = ssp_f(tv);
        tb[wave][lane] = tv;
        float w = mb2s[lane];
        for (int k = 0; k < F_DIM; k++) w += tb[wave][k] * mw2s[k * F_DIM + lane];
        atomicAdd(&agg_m[dm * F_DIM + lane], xm[sm * F_DIM + lane] * w * ccut_f(d));
    }
}

// ---------------- blend ----------------
__global__ __launch_bounds__(256) void k_blend(const float* h_local, const float* h_hier,
                                               const int* is_m, const int* invg, const float* m,
                                               float* h_out) {
    int idx = blockIdx.x * 256 + threadIdx.x;   // N*H
    int n = idx >> 7, c = idx & 127;
    float mm = m[n];
    float hh = is_m[n] ? h_hier[invg[n] * H_DIM + c] : 0.f;
    h_out[idx] = (1.f - mm) * h_local[idx] + mm * hh;
}

// ---------------- parallel segment-sum pooling ----------------
__global__ __launch_bounds__(256) void k_pool(const float* __restrict__ h, const int* __restrict__ batch,
                                              float* pooled) {
    int c = threadIdx.x & 127, a = threadIdx.x >> 7;
    int n0 = blockIdx.x * 64;
    float acc = 0.f;
    int cur = batch[n0 + a];
    for (int i = a; i < 64; i += 2) {
        int n = n0 + i;
        int b = batch[n];
        if (b != cur) { atomicAdd(&pooled[cur * H_DIM + c], acc); acc = 0.f; cur = b; }
        acc += h[n * H_DIM + c];
    }
    atomicAdd(&pooled[cur * H_DIM + c], acc);
}

// ---------------- predict MLP (dual-dtype output) ----------------
__global__ __launch_bounds__(128) void k_pred2(const float* pooled,
                                               const float* w1, const float* b1,
                                               const float* w2, const float* b2,
                                               void* outv, const int* flag) {
    __shared__ float c64[64];
    int b = blockIdx.x, t = threadIdx.x;
    if (t < 64) {
        float v = b1[t];
        for (int k = 0; k < H_DIM; k++) v += pooled[b * H_DIM + k] * w1[k * 64 + t];
        c64[t] = v * sigm_f(v);   // silu
    }
    __syncthreads();
    if (t == 0) {
        float o = b2[0];
        for (int k = 0; k < 64; k++) o += c64[k] * w2[k];
        if (flag[0]) ((float*)outv)[b] = o;
        else ((__hip_bfloat16*)outv)[b] = __float2bfloat16(o);
    }
}

extern "C" void kernel_launch(void* const* d_in, const int* in_sizes, int n_in,
                              void* d_out, int out_size, void* d_ws, size_t ws_size,
                              hipStream_t stream) {
    (void)n_in; (void)out_size; (void)ws_size;
    const int* atoms = (const int*)d_in[0];
    const int* src = (const int*)d_in[2];
    const int* dst = (const int*)d_in[3];
    const int* batch = (const int*)d_in[4];

    // -------- workspace carve (fp32) --------
    float* W = (float*)d_ws;
    int* dflag = (int*)W; W += 16;     // dtype flag (aligned pad)

    // fp32-converted copies of all float inputs (fused single conversion kernel)
    static const int fidx[25] = {1,5,6,7,8,9,10,11,12,13,14,15,16,17,18,19,20,21,22,23,24,25,26,27,28};
    float* fin[29];
    ConvArgs ca;
    float* convBase = W;
    int off = 0;
    for (int q = 0; q < 25; q++) {
        int i = fidx[q];
        ca.p[q] = d_in[i];
        ca.off[q] = off;
        fin[i] = convBase + off;
        off += in_sizes[i];
    }
    ca.off[25] = off;
    W += off;

    k_detect<<<1, 256, 0, stream>>>((const unsigned short*)d_in[5], in_sizes[5], dflag);
    k_convert_all<<<(off + 255) / 256, 256, 0, stream>>>(ca, convBase, dflag);

    const float* posf = fin[1];
    const float* embf = fin[5];

    float* h      = W; W += N_ATOMS * H_DIM;
    float* h_loc  = W; W += N_ATOMS * H_DIM;
    float* xbuf   = W; W += N_ATOMS * F_DIM;
    float* aggbuf = W; W += N_ATOMS * F_DIM;
    float* scores = W; W += N_ATOMS;
    float* mbuf   = W; W += N_ATOMS;
    float* h_m    = W; W += K_TOP * H_DIM;
    float* pos_m  = W; W += K_TOP * 3;
    float* xm     = W; W += K_TOP * F_DIM;
    float* qm     = W; W += K_TOP * S_DIM;
    float* km     = W; W += K_TOP * S_DIM;
    float* dmat   = W; W += K_TOP * K_TOP;
    float* decay  = W; W += K_TOP * K_TOP;
    float* sbuf   = W; W += K_TOP * K_TOP;
    float* hi     = W; W += K_TOP * H_DIM;
    float* hj     = W; W += K_TOP * H_DIM;
    float* agg_m  = W; W += K_TOP * F_DIM;
    float* h_hier = W; W += K_TOP * H_DIM;
    float* pooled = W; W += B_BATCH * H_DIM;
    int* rankb  = (int*)W; W += N_ATOMS;
    int* is_m   = (int*)W; W += N_ATOMS;
    int* invg   = (int*)W; W += N_ATOMS;
    int* midx   = (int*)W; W += K_TOP;
    unsigned char* adj = (unsigned char*)W; W += (K_TOP * K_TOP) / 4;
    unsigned char* Av  = (unsigned char*)W; W += (K_TOP * K_TOP) / 4;

    k_embed<<<(N_ATOMS * H_DIM) / 256, 256, 0, stream>>>(atoms, embf, h);

    for (int l = 0; l < L_LAYERS; l++) {
        const float* mw1 = fin[6]  + l * G_DIM * F_DIM;
        const float* mb1 = fin[7]  + l * F_DIM;
        const float* mw2 = fin[8]  + l * F_DIM * F_DIM;
        const float* mb2 = fin[9]  + l * F_DIM;
        const float* cf1 = fin[10] + l * H_DIM * F_DIM;
        const float* cf2w = fin[11] + l * F_DIM * H_DIM;
        const float* cf2b = fin[12] + l * H_DIM;
        const float* lw  = fin[13] + l * H_DIM * H_DIM;
        const float* lb  = fin[14] + l * H_DIM;
        const float* aw1 = fin[15] + l * (2 * H_DIM + G_DIM) * H_DIM;
        const float* ab1 = fin[16] + l * H_DIM;
        const float* aw2 = fin[17] + l * H_DIM;
        const float* ab2 = fin[18] + l;
        const float* msw1 = fin[19] + l * S_DIM * MH_DIM;
        const float* msb1 = fin[20] + l * MH_DIM;
        const float* msw2 = fin[21] + l * MH_DIM;
        const float* msb2 = fin[22] + l;
        const float* wq  = fin[23] + l * S_DIM * S_DIM;
        const float* wk  = fin[24] + l * S_DIM * S_DIM;

        k_x<<<N_ATOMS / 4, 256, 0, stream>>>(h, cf1, xbuf, N_ATOMS);
        (void)hipMemsetAsync(aggbuf, 0, N_ATOMS * F_DIM * sizeof(float), stream);
        k_edge<<<E_EDGES / EPB, 512, 0, stream>>>(posf, src, dst, xbuf, mw1, mb1, mw2, mb2, aggbuf);
        k_update<<<N_ATOMS / 4, 256, 0, stream>>>(aggbuf, h, cf2w, cf2b, lw, lb, h_loc, N_ATOMS);
        k_scores<<<N_ATOMS / 256, 256, 0, stream>>>(h_loc, msw1, msb1, msw2, msb2, scores);
        k_rank<<<N_ATOMS / 256, 256, 0, stream>>>(scores, rankb);
        k_select<<<1, 1024, 0, stream>>>(scores, rankb, is_m, invg, midx, mbuf);
        k_gather<<<(K_TOP * H_DIM) / 256, 256, 0, stream>>>(midx, h_loc, posf, h_m, pos_m);
        k_x<<<K_TOP / 4, 256, 0, stream>>>(h_m, cf1, xm, K_TOP);
        (void)hipMemsetAsync(adj, 0, K_TOP * K_TOP, stream);
        k_adj<<<E_EDGES / 256, 256, 0, stream>>>(src, dst, is_m, invg, adj);
        k_qk<<<(K_TOP * 32) / 256, 256, 0, stream>>>(h_m, wq, wk, qm, km);
        k_attn<<<K_TOP, 256, 0, stream>>>(qm, km, adj, Av);
        k_dmat<<<(K_TOP * K_TOP) / 256, 256, 0, stream>>>(pos_m, dmat);
        k_hij<<<(2 * K_TOP) / 4, 256, 0, stream>>>(h_m, aw1, hi, hj);
        k_score<<<K_TOP * 2, 512, 0, stream>>>(hi, hj, aw1, ab1, aw2, ab2, dmat, Av, sbuf);
        k_decay<<<K_TOP, 256, 0, stream>>>(sbuf, decay);
        (void)hipMemsetAsync(agg_m, 0, K_TOP * F_DIM * sizeof(float), stream);
        k_aggd<<<K_TOP * AGGD_SPLIT, 512, 0, stream>>>(xm, dmat, decay, Av, mw1, mb1, mw2, mb2, agg_m);
        k_aggs<<<E_EDGES / EPB, 512, 0, stream>>>(pos_m, src, dst, is_m, invg, xm,
                                                  mw1, mb1, mw2, mb2, agg_m);
        k_update<<<K_TOP / 4, 256, 0, stream>>>(agg_m, h_m, cf2w, cf2b, lw, lb, h_hier, K_TOP);
        k_blend<<<(N_ATOMS * H_DIM) / 256, 256, 0, stream>>>(h_loc, h_hier, is_m, invg, mbuf, h);
    }

    (void)hipMemsetAsync(pooled, 0, B_BATCH * H_DIM * sizeof(float), stream);
    k_pool<<<N_ATOMS / 64, 256, 0, stream>>>(h, batch, pooled);
    k_pred2<<<B_BATCH, 128, 0, stream>>>(pooled, fin[25], fin[26], fin[27], fin[28], d_out, dflag);
}

// Round 6
// 883.685 us; speedup vs baseline: 1.1253x; 1.1253x over previous
//
#include <hip/hip_runtime.h>
#include <hip/hip_bf16.h>
#include <math.h>

#define N_ATOMS 2048
#define E_EDGES 65536
#define B_BATCH 8
#define H_DIM 128
#define G_DIM 50
#define F_DIM 64
#define S_DIM 16
#define MH_DIM 32
#define K_TOP 512
#define L_LAYERS 2
#define EPW 8           // edges per wave in k_edge/k_aggs (4 waves/block -> 32 edges/block)
#define AGGD_SPLIT 4
#define SCORE_SPLIT 4

static constexpr float STEP   = 10.0f / 49.0f;          // OFFSET spacing
static constexpr float COEFF  = -12.005f;               // -0.5/STEP^2
static constexpr float PI10   = 0.31415926535897931f;   // pi/CUTOFF
static constexpr float LN2    = 0.69314718055994531f;
static constexpr float LAMBDA = 0.002f;

#define DEV static __device__ __forceinline__

DEV float ssp_f(float x) { return fmaxf(x, 0.f) + log1pf(expf(-fabsf(x))) - LN2; }
DEV float ccut_f(float d) { return 0.5f * (cosf(d * PI10) + 1.f); }
DEV float sigm_f(float x) { return 1.f / (1.f + expf(-x)); }

// ---------------- dtype detect: bf16-interp of fp32 data shows huge/NaN values ----------------
__global__ __launch_bounds__(256) void k_detect(const unsigned short* raw, int n, int* flag) {
    __shared__ int any;
    if (threadIdx.x == 0) any = 0;
    __syncthreads();
    for (int i = threadIdx.x; i < n; i += 256) {
        unsigned int bits = ((unsigned int)raw[i]) << 16;
        float f = __uint_as_float(bits);
        if (!(fabsf(f) <= 1e10f)) any = 1;   // catches NaN and huge => source is fp32
    }
    __syncthreads();
    if (threadIdx.x == 0) flag[0] = any;
}

// ---------------- fused convert of all float inputs -> fp32 workspace ----------------
struct ConvArgs {
    const void* p[25];
    int off[26];     // prefix offsets into dst; off[25] = total
};

__global__ __launch_bounds__(256) void k_convert_all(ConvArgs a, float* dst, const int* flag) {
    int i = blockIdx.x * 256 + threadIdx.x;
    int total = a.off[25];
    if (i >= total) return;
    int seg = 0;
    while (i >= a.off[seg + 1]) seg++;
    int k = i - a.off[seg];
    if (flag[0]) {
        dst[i] = ((const float*)a.p[seg])[k];
    } else {
        unsigned int bits = ((unsigned int)((const unsigned short*)a.p[seg])[k]) << 16;
        dst[i] = __uint_as_float(bits);
    }
}

// ---------------- embedding ----------------
__global__ __launch_bounds__(256) void k_embed(const int* atoms, const float* emb, float* h) {
    int i = blockIdx.x * 256 + threadIdx.x;     // N*H
    int n = i >> 7, c = i & 127;
    h[i] = emb[atoms[n] * H_DIM + c];
}

// ---------------- x = h @ cf1  (M x 128 @ 128 x 64) ----------------
__global__ __launch_bounds__(256) void k_x(const float* __restrict__ h, const float* __restrict__ cf1,
                                           float* __restrict__ x, int M) {
    int wave = threadIdx.x >> 6, lane = threadIdx.x & 63;
    int n = blockIdx.x * 4 + wave;
    if (n >= M) return;
    float acc = 0.f;
    for (int k = 0; k < H_DIM; k++) acc += h[n * H_DIM + k] * cf1[k * F_DIM + lane];
    x[n * F_DIM + lane] = acc;
}

// ---------------- edge filter + scatter into agg (atomic), register weights ----------------
__global__ __launch_bounds__(256) void k_edge(const float* pos, const int* src, const int* dst,
                                              const float* x,
                                              const float* mw1, const float* mb1,
                                              const float* mw2, const float* mb2,
                                              float* agg) {
    __shared__ float gbuf[4][G_DIM], tbuf[4][F_DIM];
    int t = threadIdx.x, wave = t >> 6, lane = t & 63;
    float w1r[G_DIM], w2r[F_DIM];
    #pragma unroll
    for (int g = 0; g < G_DIM; g++) w1r[g] = mw1[g * F_DIM + lane];
    #pragma unroll
    for (int k = 0; k < F_DIM; k++) w2r[k] = mw2[k * F_DIM + lane];
    float b1 = mb1[lane], b2v = mb2[lane];
    int e0 = blockIdx.x * (4 * EPW) + wave * EPW;
    for (int ee = 0; ee < EPW; ee++) {
        int e = e0 + ee;
        int sI = src[e], dI = dst[e];
        float dx = pos[sI * 3 + 0] - pos[dI * 3 + 0];
        float dy = pos[sI * 3 + 1] - pos[dI * 3 + 1];
        float dz = pos[sI * 3 + 2] - pos[dI * 3 + 2];
        float d = sqrtf(dx * dx + dy * dy + dz * dz + 1e-12f);
        if (lane < G_DIM) { float u = d - lane * STEP; gbuf[wave][lane] = expf(COEFF * u * u); }
        // wave-lockstep: per-wave LDS buffers need no barrier
        float tv = b1;
        #pragma unroll
        for (int g = 0; g < G_DIM; g++) tv += gbuf[wave][g] * w1r[g];
        tv = ssp_f(tv);
        tbuf[wave][lane] = tv;
        float w = b2v;
        #pragma unroll
        for (int k = 0; k < F_DIM; k++) w += tbuf[wave][k] * w2r[k];
        w *= ccut_f(d);
        atomicAdd(&agg[dI * F_DIM + lane], x[sI * F_DIM + lane] * w);
    }
}

// ---------------- out = base + ssp(agg@cf2w + cf2b) @ lw + lb ----------------
__global__ __launch_bounds__(256) void k_update(const float* __restrict__ agg, const float* __restrict__ base,
                                                const float* cf2w, const float* cf2b,
                                                const float* lw, const float* lb,
                                                float* out, int M) {
    __shared__ float tbuf[4][H_DIM];
    int wave = threadIdx.x >> 6, lane = threadIdx.x & 63;
    int n = blockIdx.x * 4 + wave;
    float t0 = cf2b[lane], t1 = cf2b[lane + 64];
    if (n < M) {
        for (int f = 0; f < F_DIM; f++) {
            float a = agg[n * F_DIM + f];
            t0 += a * cf2w[f * H_DIM + lane];
            t1 += a * cf2w[f * H_DIM + lane + 64];
        }
    }
    tbuf[wave][lane] = ssp_f(t0);
    tbuf[wave][lane + 64] = ssp_f(t1);
    __syncthreads();
    if (n < M) {
        float o0 = lb[lane], o1 = lb[lane + 64];
        for (int k = 0; k < H_DIM; k++) {
            float tv = tbuf[wave][k];
            o0 += tv * lw[k * H_DIM + lane];
            o1 += tv * lw[k * H_DIM + lane + 64];
        }
        out[n * H_DIM + lane]      = base[n * H_DIM + lane] + o0;
        out[n * H_DIM + lane + 64] = base[n * H_DIM + lane + 64] + o1;
    }
}

// ---------------- node scores ----------------
__global__ __launch_bounds__(256) void k_scores(const float* h_local,
                                                const float* msw1, const float* msb1,
                                                const float* msw2, const float* msb2,
                                                float* scores) {
    int n = blockIdx.x * 256 + threadIdx.x;
    if (n >= N_ATOMS) return;
    float hs[S_DIM];
    for (int s = 0; s < S_DIM; s++) hs[s] = h_local[n * H_DIM + s];
    float sc = msb2[0];
    for (int j = 0; j < MH_DIM; j++) {
        float v = msb1[j];
        for (int s = 0; s < S_DIM; s++) v += hs[s] * msw1[s * MH_DIM + j];
        sc += fmaxf(v, 0.f) * msw2[j];
    }
    scores[n] = sc;
}

// ---------------- exact rank (ties -> lower index wins, matching top_k) ----------------
__global__ __launch_bounds__(256) void k_rank(const float* scores, int* rank) {
    __shared__ float s[N_ATOMS];
    for (int i = threadIdx.x; i < N_ATOMS; i += 256) s[i] = scores[i];
    __syncthreads();
    int i = blockIdx.x * 256 + threadIdx.x;
    float si = s[i];
    int r = 0;
    for (int j = 0; j < N_ATOMS; j++) {
        float sj = s[j];
        r += (sj > si) || (sj == si && j < i);
    }
    rank[i] = r;
}

// ---------------- selection, prefix, midx, m ----------------
__global__ __launch_bounds__(1024) void k_select(const float* scores, const int* rank,
                                                 int* is_m, int* invg, int* midx, float* m) {
    __shared__ int flag[N_ATOMS];
    __shared__ int bufA[N_ATOMS], bufB[N_ATOMS];
    __shared__ float kth;
    int t = threadIdx.x;
    for (int i = t; i < N_ATOMS; i += 1024) {
        int f = rank[i] < K_TOP;
        flag[i] = f;
        bufA[i] = f;
        if (rank[i] == K_TOP - 1) kth = scores[i];
    }
    __syncthreads();
    int* in = bufA;
    int* out = bufB;
    for (int d = 1; d < N_ATOMS; d <<= 1) {
        for (int i = t; i < N_ATOMS; i += 1024) out[i] = in[i] + (i >= d ? in[i - d] : 0);
        __syncthreads();
        int* tmp = in; in = out; out = tmp;
    }
    float kv = kth;
    for (int i = t; i < N_ATOMS; i += 1024) {
        int f = flag[i];
        int pos = in[i] - f;   // exclusive prefix
        is_m[i] = f;
        invg[i] = f ? pos : 0;
        if (f) midx[pos] = i;
        m[i] = sigm_f(scores[i] - kv + 1e-6f);
    }
}

// ---------------- gather h_m / pos_m ----------------
__global__ __launch_bounds__(256) void k_gather(const int* midx, const float* h_local,
                                                const float* pos, float* h_m, float* pos_m) {
    int i = blockIdx.x * 256 + threadIdx.x;  // K*H
    int k = i >> 7, c = i & 127;
    int n = midx[k];
    h_m[i] = h_local[n * H_DIM + c];
    if (c < 3) pos_m[k * 3 + c] = pos[n * 3 + c];
}

// ---------------- adjacency among selected ----------------
__global__ __launch_bounds__(256) void k_adj(const int* src, const int* dst, const int* is_m,
                                             const int* invg, unsigned char* adj) {
    int e = blockIdx.x * 256 + threadIdx.x;
    int s = src[e], d = dst[e];
    if (is_m[s] && is_m[d]) adj[invg[s] * K_TOP + invg[d]] = 1;
}

// ---------------- q/k projections (S=16), 256-thread blocks ----------------
__global__ __launch_bounds__(256) void k_qk(const float* h_m, const float* wq,
                                            const float* wk, float* qm, float* km) {
    int gid = blockIdx.x * 256 + threadIdx.x;   // K*32
    int r = gid >> 5, t = gid & 31;
    const float* w = (t < 16) ? wq : wk;
    int c = t & 15;
    float acc = 0.f;
    for (int s = 0; s < S_DIM; s++) acc += h_m[r * H_DIM + s] * w[s * S_DIM + c];
    if (t < 16) qm[r * S_DIM + c] = acc; else km[r * S_DIM + c] = acc;
}

// ---------------- attention softmax -> Av mask ----------------
__global__ __launch_bounds__(256) void k_attn(const float* qm, const float* km,
                                              const unsigned char* adj, unsigned char* Av) {
    __shared__ float lrow[K_TOP];
    __shared__ float red[256];
    int i = blockIdx.x, t = threadIdx.x;
    float q[S_DIM];
    for (int s = 0; s < S_DIM; s++) q[s] = qm[i * S_DIM + s];
    for (int j = t; j < K_TOP; j += 256) {
        float acc = 0.f;
        for (int s = 0; s < S_DIM; s++) acc += q[s] * km[j * S_DIM + s];
        lrow[j] = acc * 0.25f;   // / sqrt(16)
    }
    __syncthreads();
    float mx = -1e30f;
    for (int j = t; j < K_TOP; j += 256) mx = fmaxf(mx, lrow[j]);
    red[t] = mx; __syncthreads();
    for (int o = 128; o > 0; o >>= 1) { if (t < o) red[t] = fmaxf(red[t], red[t + o]); __syncthreads(); }
    mx = red[0]; __syncthreads();
    float sum = 0.f;
    for (int j = t; j < K_TOP; j += 256) sum += expf(lrow[j] - mx);
    red[t] = sum; __syncthreads();
    for (int o = 128; o > 0; o >>= 1) { if (t < o) red[t] += red[t + o]; __syncthreads(); }
    float inv_s = 1.f / red[0];
    for (int j = t; j < K_TOP; j += 256) {
        float a = expf(lrow[j] - mx) * inv_s;
        Av[i * K_TOP + j] = (a > LAMBDA) && (!adj[i * K_TOP + j]) && (i != j);
    }
}

// ---------------- pairwise distances ----------------
__global__ __launch_bounds__(256) void k_dmat(const float* pos_m, float* dmat) {
    int idx = blockIdx.x * 256 + threadIdx.x;   // K*K
    int i = idx >> 9, j = idx & (K_TOP - 1);
    float dx = pos_m[i * 3 + 0] - pos_m[j * 3 + 0];
    float dy = pos_m[i * 3 + 1] - pos_m[j * 3 + 1];
    float dz = pos_m[i * 3 + 2] - pos_m[j * 3 + 2];
    dmat[idx] = sqrtf(dx * dx + dy * dy + dz * dz + 1e-12f);
}

// ---------------- hi = h_m@Wi, hj = h_m@Wj ----------------
__global__ __launch_bounds__(256) void k_hij(const float* h_m, const float* aw1,
                                             float* hi, float* hj) {
    int wave = threadIdx.x >> 6, lane = threadIdx.x & 63;
    int idx = blockIdx.x * 4 + wave;            // 0..1023
    int which = idx >> 9;
    int r = idx & (K_TOP - 1);
    const float* W = aw1 + which * H_DIM * H_DIM;
    float o0 = 0.f, o1 = 0.f;
    for (int k = 0; k < H_DIM; k++) {
        float hv = h_m[r * H_DIM + k];
        o0 += hv * W[k * H_DIM + lane];
        o1 += hv * W[k * H_DIM + lane + 64];
    }
    float* out = which ? hj : hi;
    out[r * H_DIM + lane] = o0;
    out[r * H_DIM + lane + 64] = o1;
}

// ---------------- per-row attention scores, register Wd columns ----------------
__global__ __launch_bounds__(256) void k_score(const float* hi, const float* hj,
                                               const float* aw1, const float* ab1,
                                               const float* aw2, const float* ab2,
                                               const float* dmat, const unsigned char* Av,
                                               float* sbuf) {
    __shared__ float gbuf[4][G_DIM];
    int i = blockIdx.x & (K_TOP - 1), part = blockIdx.x >> 9;
    int t = threadIdx.x, wave = t >> 6, lane = t & 63;
    const float* wd = aw1 + 2 * H_DIM * H_DIM;
    float wdr0[G_DIM], wdr1[G_DIM];
    #pragma unroll
    for (int g = 0; g < G_DIM; g++) {
        wdr0[g] = wd[g * H_DIM + lane];
        wdr1[g] = wd[g * H_DIM + lane + 64];
    }
    float his0 = hi[i * H_DIM + lane], his1 = hi[i * H_DIM + lane + 64];
    float ab0 = ab1[lane], ab1v = ab1[lane + 64];
    float aw0 = aw2[lane], aw1v = aw2[lane + 64];
    float b2 = ab2[0];
    int jbase = part * (K_TOP / SCORE_SPLIT);
    for (int j = jbase + wave; j < jbase + K_TOP / SCORE_SPLIT; j += 4) {
        bool act = Av[i * K_TOP + j] != 0;
        float sc = -1e9f;
        if (act) {
            float dd = dmat[i * K_TOP + j];
            if (lane < G_DIM) { float u = dd - lane * STEP; gbuf[wave][lane] = expf(COEFF * u * u); }
            float v0 = his0 + hj[j * H_DIM + lane] + ab0;
            float v1 = his1 + hj[j * H_DIM + lane + 64] + ab1v;
            #pragma unroll
            for (int g = 0; g < G_DIM; g++) {
                float gv = gbuf[wave][g];
                v0 += gv * wdr0[g];
                v1 += gv * wdr1[g];
            }
            float p = fmaxf(v0, 0.f) * aw0 + fmaxf(v1, 0.f) * aw1v;
            for (int o = 1; o < 64; o <<= 1) p += __shfl_xor(p, o);
            sc = p + b2;
        }
        if (lane == 0) sbuf[i * K_TOP + j] = sc;
    }
}

// ---------------- row softmax over sbuf -> decay ----------------
__global__ __launch_bounds__(256) void k_decay(const float* sbuf, float* decay) {
    __shared__ float srow[K_TOP];
    __shared__ float red[256];
    int i = blockIdx.x, t = threadIdx.x;
    for (int j = t; j < K_TOP; j += 256) srow[j] = sbuf[i * K_TOP + j];
    __syncthreads();
    float mx = -1e30f;
    for (int j = t; j < K_TOP; j += 256) mx = fmaxf(mx, srow[j]);
    red[t] = mx; __syncthreads();
    for (int o = 128; o > 0; o >>= 1) { if (t < o) red[t] = fmaxf(red[t], red[t + o]); __syncthreads(); }
    mx = red[0]; __syncthreads();
    float sum = 0.f;
    for (int j = t; j < K_TOP; j += 256) sum += (srow[j] > -5e8f) ? expf(srow[j] - mx) : 0.f;
    red[t] = sum; __syncthreads();
    for (int o = 128; o > 0; o >>= 1) { if (t < o) red[t] += red[t + o]; __syncthreads(); }
    float s_total = red[0];
    float inv_s = (s_total > 0.f) ? 1.f / s_total : 0.f;
    for (int j = t; j < K_TOP; j += 256)
        decay[i * K_TOP + j] = (srow[j] > -5e8f) ? expf(srow[j] - mx) * inv_s : 0.f;
}

// ---------------- agg_d: register weights, i-range split, atomic merge ----------------
__global__ __launch_bounds__(256) void k_aggd(const float* xm, const float* dmat, const float* decay,
                                              const unsigned char* Av,
                                              const float* mw1, const float* mb1,
                                              const float* mw2, const float* mb2,
                                              float* agg_m) {
    __shared__ float gbuf[4][G_DIM], tbuf[4][F_DIM];
    __shared__ float accs[4][F_DIM];
    int j = blockIdx.x & (K_TOP - 1), part = blockIdx.x >> 9;
    int t = threadIdx.x, wave = t >> 6, lane = t & 63;
    float w1r[G_DIM], w2r[F_DIM];
    #pragma unroll
    for (int g = 0; g < G_DIM; g++) w1r[g] = mw1[g * F_DIM + lane];
    #pragma unroll
    for (int k = 0; k < F_DIM; k++) w2r[k] = mw2[k * F_DIM + lane];
    float b1 = mb1[lane], b2v = mb2[lane];
    float acc = 0.f;
    int ibase = part * (K_TOP / AGGD_SPLIT);
    for (int i = ibase + wave; i < ibase + K_TOP / AGGD_SPLIT; i += 4) {
        if (!Av[i * K_TOP + j]) continue;
        float dd = dmat[i * K_TOP + j];
        float dec = decay[i * K_TOP + j];
        if (lane < G_DIM) { float u = dd - lane * STEP; gbuf[wave][lane] = expf(COEFF * u * u) * dec; }
        float tv = b1;
        #pragma unroll
        for (int g = 0; g < G_DIM; g++) tv += gbuf[wave][g] * w1r[g];
        tv = ssp_f(tv);
        tbuf[wave][lane] = tv;
        float w = b2v;
        #pragma unroll
        for (int k = 0; k < F_DIM; k++) w += tbuf[wave][k] * w2r[k];
        acc += xm[i * F_DIM + lane] * w * ccut_f(dd);
    }
    accs[wave][lane] = acc;
    __syncthreads();
    if (wave == 0) {
        float s = accs[0][lane] + accs[1][lane] + accs[2][lane] + accs[3][lane];
        atomicAdd(&agg_m[j * F_DIM + lane], s);
    }
}

// ---------------- valid-edge filter scatter into agg_m, register weights ----------------
__global__ __launch_bounds__(256) void k_aggs(const float* pos_m, const int* src, const int* dst,
                                              const int* is_m, const int* invg, const float* xm,
                                              const float* mw1, const float* mb1,
                                              const float* mw2, const float* mb2,
                                              float* agg_m) {
    __shared__ float gbuf[4][G_DIM], tbuf[4][F_DIM];
    int t = threadIdx.x, wave = t >> 6, lane = t & 63;
    float w1r[G_DIM], w2r[F_DIM];
    #pragma unroll
    for (int g = 0; g < G_DIM; g++) w1r[g] = mw1[g * F_DIM + lane];
    #pragma unroll
    for (int k = 0; k < F_DIM; k++) w2r[k] = mw2[k * F_DIM + lane];
    float b1 = mb1[lane], b2v = mb2[lane];
    int e0 = blockIdx.x * (4 * EPW) + wave * EPW;
    for (int ee = 0; ee < EPW; ee++) {
        int e = e0 + ee;
        int s = src[e], dn = dst[e];
        bool valid = is_m[s] && is_m[dn];
        if (!valid) continue;
        int sm = invg[s];
        int dm = invg[dn];
        float dx = pos_m[sm * 3 + 0] - pos_m[dm * 3 + 0];
        float dy = pos_m[sm * 3 + 1] - pos_m[dm * 3 + 1];
        float dz = pos_m[sm * 3 + 2] - pos_m[dm * 3 + 2];
        float d = sqrtf(dx * dx + dy * dy + dz * dz + 1e-12f);
        if (lane < G_DIM) { float u = d - lane * STEP; gbuf[wave][lane] = expf(COEFF * u * u); }
        float tv = b1;
        #pragma unroll
        for (int g = 0; g < G_DIM; g++) tv += gbuf[wave][g] * w1r[g];
        tv = ssp_f(tv);
        tbuf[wave][lane] = tv;
        float w = b2v;
        #pragma unroll
        for (int k = 0; k < F_DIM; k++) w += tbuf[wave][k] * w2r[k];
        atomicAdd(&agg_m[dm * F_DIM + lane], xm[sm * F_DIM + lane] * w * ccut_f(d));
    }
}

// ---------------- blend ----------------
__global__ __launch_bounds__(256) void k_blend(const float* h_local, const float* h_hier,
                                               const int* is_m, const int* invg, const float* m,
                                               float* h_out) {
    int idx = blockIdx.x * 256 + threadIdx.x;   // N*H
    int n = idx >> 7, c = idx & 127;
    float mm = m[n];
    float hh = is_m[n] ? h_hier[invg[n] * H_DIM + c] : 0.f;
    h_out[idx] = (1.f - mm) * h_local[idx] + mm * hh;
}

// ---------------- parallel segment-sum pooling ----------------
__global__ __launch_bounds__(256) void k_pool(const float* __restrict__ h, const int* __restrict__ batch,
                                              float* pooled) {
    int c = threadIdx.x & 127, a = threadIdx.x >> 7;
    int n0 = blockIdx.x * 64;
    float acc = 0.f;
    int cur = batch[n0 + a];
    for (int i = a; i < 64; i += 2) {
        int n = n0 + i;
        int b = batch[n];
        if (b != cur) { atomicAdd(&pooled[cur * H_DIM + c], acc); acc = 0.f; cur = b; }
        acc += h[n * H_DIM + c];
    }
    atomicAdd(&pooled[cur * H_DIM + c], acc);
}

// ---------------- predict MLP (dual-dtype output) ----------------
__global__ __launch_bounds__(128) void k_pred2(const float* pooled,
                                               const float* w1, const float* b1,
                                               const float* w2, const float* b2,
                                               void* outv, const int* flag) {
    __shared__ float c64[64];
    int b = blockIdx.x, t = threadIdx.x;
    if (t < 64) {
        float v = b1[t];
        for (int k = 0; k < H_DIM; k++) v += pooled[b * H_DIM + k] * w1[k * 64 + t];
        c64[t] = v * sigm_f(v);   // silu
    }
    __syncthreads();
    if (t == 0) {
        float o = b2[0];
        for (int k = 0; k < 64; k++) o += c64[k] * w2[k];
        if (flag[0]) ((float*)outv)[b] = o;
        else ((__hip_bfloat16*)outv)[b] = __float2bfloat16(o);
    }
}

extern "C" void kernel_launch(void* const* d_in, const int* in_sizes, int n_in,
                              void* d_out, int out_size, void* d_ws, size_t ws_size,
                              hipStream_t stream) {
    (void)n_in; (void)out_size; (void)ws_size;
    const int* atoms = (const int*)d_in[0];
    const int* src = (const int*)d_in[2];
    const int* dst = (const int*)d_in[3];
    const int* batch = (const int*)d_in[4];

    // -------- workspace carve (fp32) --------
    float* W = (float*)d_ws;
    int* dflag = (int*)W; W += 16;     // dtype flag (aligned pad)

    // fp32-converted copies of all float inputs (fused single conversion kernel)
    static const int fidx[25] = {1,5,6,7,8,9,10,11,12,13,14,15,16,17,18,19,20,21,22,23,24,25,26,27,28};
    float* fin[29];
    ConvArgs ca;
    float* convBase = W;
    int off = 0;
    for (int q = 0; q < 25; q++) {
        int i = fidx[q];
        ca.p[q] = d_in[i];
        ca.off[q] = off;
        fin[i] = convBase + off;
        off += in_sizes[i];
    }
    ca.off[25] = off;
    W += off;

    k_detect<<<1, 256, 0, stream>>>((const unsigned short*)d_in[5], in_sizes[5], dflag);
    k_convert_all<<<(off + 255) / 256, 256, 0, stream>>>(ca, convBase, dflag);

    const float* posf = fin[1];
    const float* embf = fin[5];

    float* h      = W; W += N_ATOMS * H_DIM;
    float* h_loc  = W; W += N_ATOMS * H_DIM;
    float* xbuf   = W; W += N_ATOMS * F_DIM;
    float* aggbuf = W; W += N_ATOMS * F_DIM;
    float* scores = W; W += N_ATOMS;
    float* mbuf   = W; W += N_ATOMS;
    float* h_m    = W; W += K_TOP * H_DIM;
    float* pos_m  = W; W += K_TOP * 3;
    float* xm     = W; W += K_TOP * F_DIM;
    float* qm     = W; W += K_TOP * S_DIM;
    float* km     = W; W += K_TOP * S_DIM;
    float* dmat   = W; W += K_TOP * K_TOP;
    float* decay  = W; W += K_TOP * K_TOP;
    float* sbuf   = W; W += K_TOP * K_TOP;
    float* hi     = W; W += K_TOP * H_DIM;
    float* hj     = W; W += K_TOP * H_DIM;
    float* agg_m  = W; W += K_TOP * F_DIM;
    float* h_hier = W; W += K_TOP * H_DIM;
    float* pooled = W; W += B_BATCH * H_DIM;
    int* rankb  = (int*)W; W += N_ATOMS;
    int* is_m   = (int*)W; W += N_ATOMS;
    int* invg   = (int*)W; W += N_ATOMS;
    int* midx   = (int*)W; W += K_TOP;
    unsigned char* adj = (unsigned char*)W; W += (K_TOP * K_TOP) / 4;
    unsigned char* Av  = (unsigned char*)W; W += (K_TOP * K_TOP) / 4;

    k_embed<<<(N_ATOMS * H_DIM) / 256, 256, 0, stream>>>(atoms, embf, h);

    for (int l = 0; l < L_LAYERS; l++) {
        const float* mw1 = fin[6]  + l * G_DIM * F_DIM;
        const float* mb1 = fin[7]  + l * F_DIM;
        const float* mw2 = fin[8]  + l * F_DIM * F_DIM;
        const float* mb2 = fin[9]  + l * F_DIM;
        const float* cf1 = fin[10] + l * H_DIM * F_DIM;
        const float* cf2w = fin[11] + l * F_DIM * H_DIM;
        const float* cf2b = fin[12] + l * H_DIM;
        const float* lw  = fin[13] + l * H_DIM * H_DIM;
        const float* lb  = fin[14] + l * H_DIM;
        const float* aw1 = fin[15] + l * (2 * H_DIM + G_DIM) * H_DIM;
        const float* ab1 = fin[16] + l * H_DIM;
        const float* aw2 = fin[17] + l * H_DIM;
        const float* ab2 = fin[18] + l;
        const float* msw1 = fin[19] + l * S_DIM * MH_DIM;
        const float* msb1 = fin[20] + l * MH_DIM;
        const float* msw2 = fin[21] + l * MH_DIM;
        const float* msb2 = fin[22] + l;
        const float* wq  = fin[23] + l * S_DIM * S_DIM;
        const float* wk  = fin[24] + l * S_DIM * S_DIM;

        k_x<<<N_ATOMS / 4, 256, 0, stream>>>(h, cf1, xbuf, N_ATOMS);
        (void)hipMemsetAsync(aggbuf, 0, N_ATOMS * F_DIM * sizeof(float), stream);
        k_edge<<<E_EDGES / (4 * EPW), 256, 0, stream>>>(posf, src, dst, xbuf, mw1, mb1, mw2, mb2, aggbuf);
        k_update<<<N_ATOMS / 4, 256, 0, stream>>>(aggbuf, h, cf2w, cf2b, lw, lb, h_loc, N_ATOMS);
        k_scores<<<N_ATOMS / 256, 256, 0, stream>>>(h_loc, msw1, msb1, msw2, msb2, scores);
        k_rank<<<N_ATOMS / 256, 256, 0, stream>>>(scores, rankb);
        k_select<<<1, 1024, 0, stream>>>(scores, rankb, is_m, invg, midx, mbuf);
        k_gather<<<(K_TOP * H_DIM) / 256, 256, 0, stream>>>(midx, h_loc, posf, h_m, pos_m);
        k_x<<<K_TOP / 4, 256, 0, stream>>>(h_m, cf1, xm, K_TOP);
        (void)hipMemsetAsync(adj, 0, K_TOP * K_TOP, stream);
        k_adj<<<E_EDGES / 256, 256, 0, stream>>>(src, dst, is_m, invg, adj);
        k_qk<<<(K_TOP * 32) / 256, 256, 0, stream>>>(h_m, wq, wk, qm, km);
        k_attn<<<K_TOP, 256, 0, stream>>>(qm, km, adj, Av);
        k_dmat<<<(K_TOP * K_TOP) / 256, 256, 0, stream>>>(pos_m, dmat);
        k_hij<<<(2 * K_TOP) / 4, 256, 0, stream>>>(h_m, aw1, hi, hj);
        k_score<<<K_TOP * SCORE_SPLIT, 256, 0, stream>>>(hi, hj, aw1, ab1, aw2, ab2, dmat, Av, sbuf);
        k_decay<<<K_TOP, 256, 0, stream>>>(sbuf, decay);
        (void)hipMemsetAsync(agg_m, 0, K_TOP * F_DIM * sizeof(float), stream);
        k_aggd<<<K_TOP * AGGD_SPLIT, 256, 0, stream>>>(xm, dmat, decay, Av, mw1, mb1, mw2, mb2, agg_m);
        k_aggs<<<E_EDGES / (4 * EPW), 256, 0, stream>>>(pos_m, src, dst, is_m, invg, xm,
                                                        mw1, mb1, mw2, mb2, agg_m);
        k_update<<<K_TOP / 4, 256, 0, stream>>>(agg_m, h_m, cf2w, cf2b, lw, lb, h_hier, K_TOP);
        k_blend<<<(N_ATOMS * H_DIM) / 256, 256, 0, stream>>>(h_loc, h_hier, is_m, invg, mbuf, h);
    }

    (void)hipMemsetAsync(pooled, 0, B_BATCH * H_DIM * sizeof(float), stream);
    k_pool<<<N_ATOMS / 64, 256, 0, stream>>>(h, batch, pooled);
    k_pred2<<<B_BATCH, 128, 0, stream>>>(pooled, fin[25], fin[26], fin[27], fin[28], d_out, dflag);
}

// Round 7
// 850.219 us; speedup vs baseline: 1.1696x; 1.0394x over previous
//
#include <hip/hip_runtime.h>
#include <hip/hip_bf16.h>
#include <math.h>

#define N_ATOMS 2048
#define E_EDGES 65536
#define B_BATCH 8
#define H_DIM 128
#define G_DIM 50
#define F_DIM 64
#define S_DIM 16
#define MH_DIM 32
#define K_TOP 512
#define L_LAYERS 2
#define EPW 8           // edges per wave in k_edge (4 waves/block -> 32 edges/block)

static constexpr float STEP   = 10.0f / 49.0f;          // OFFSET spacing
static constexpr float COEFF  = -12.005f;               // -0.5/STEP^2
static constexpr float PI10   = 0.31415926535897931f;   // pi/CUTOFF
static constexpr float LN2    = 0.69314718055994531f;
static constexpr float LAMBDA = 0.002f;

#define DEV static __device__ __forceinline__

DEV float ssp_f(float x) { return fmaxf(x, 0.f) + log1pf(expf(-fabsf(x))) - LN2; }
DEV float ccut_f(float d) { return 0.5f * (cosf(d * PI10) + 1.f); }
DEV float sigm_f(float x) { return 1.f / (1.f + expf(-x)); }

// ---------------- dtype detect: bf16-interp of fp32 data shows huge/NaN values ----------------
__global__ __launch_bounds__(256) void k_detect(const unsigned short* raw, int n, int* flag) {
    __shared__ int any;
    if (threadIdx.x == 0) any = 0;
    __syncthreads();
    for (int i = threadIdx.x; i < n; i += 256) {
        unsigned int bits = ((unsigned int)raw[i]) << 16;
        float f = __uint_as_float(bits);
        if (!(fabsf(f) <= 1e10f)) any = 1;   // catches NaN and huge => source is fp32
    }
    __syncthreads();
    if (threadIdx.x == 0) flag[0] = any;
}

// ---------------- fused convert of all float inputs -> fp32 workspace ----------------
struct ConvArgs {
    const void* p[25];
    int off[26];     // prefix offsets into dst; off[25] = total
};

__global__ __launch_bounds__(256) void k_convert_all(ConvArgs a, float* dst, const int* flag) {
    int i = blockIdx.x * 256 + threadIdx.x;
    int total = a.off[25];
    if (i >= total) return;
    int seg = 0;
    while (i >= a.off[seg + 1]) seg++;
    int k = i - a.off[seg];
    if (flag[0]) {
        dst[i] = ((const float*)a.p[seg])[k];
    } else {
        unsigned int bits = ((unsigned int)((const unsigned short*)a.p[seg])[k]) << 16;
        dst[i] = __uint_as_float(bits);
    }
}

// ---------------- embedding ----------------
__global__ __launch_bounds__(256) void k_embed(const int* atoms, const float* emb, float* h) {
    int i = blockIdx.x * 256 + threadIdx.x;     // N*H
    int n = i >> 7, c = i & 127;
    h[i] = emb[atoms[n] * H_DIM + c];
}

// ---------------- x = h @ cf1  (M x 128 @ 128 x 64) ----------------
__global__ __launch_bounds__(256) void k_x(const float* __restrict__ h, const float* __restrict__ cf1,
                                           float* __restrict__ x, int M) {
    int wave = threadIdx.x >> 6, lane = threadIdx.x & 63;
    int n = blockIdx.x * 4 + wave;
    if (n >= M) return;
    float acc = 0.f;
    for (int k = 0; k < H_DIM; k++) acc += h[n * H_DIM + k] * cf1[k * F_DIM + lane];
    x[n * F_DIM + lane] = acc;
}

// ---------------- edge filter + scatter into agg (atomic), register weights ----------------
__global__ __launch_bounds__(256) void k_edge(const float* pos, const int* src, const int* dst,
                                              const float* x,
                                              const float* mw1, const float* mb1,
                                              const float* mw2, const float* mb2,
                                              float* agg) {
    __shared__ float gbuf[4][G_DIM], tbuf[4][F_DIM];
    int t = threadIdx.x, wave = t >> 6, lane = t & 63;
    float w1r[G_DIM], w2r[F_DIM];
    #pragma unroll
    for (int g = 0; g < G_DIM; g++) w1r[g] = mw1[g * F_DIM + lane];
    #pragma unroll
    for (int k = 0; k < F_DIM; k++) w2r[k] = mw2[k * F_DIM + lane];
    float b1 = mb1[lane], b2v = mb2[lane];
    int e0 = blockIdx.x * (4 * EPW) + wave * EPW;
    for (int ee = 0; ee < EPW; ee++) {
        int e = e0 + ee;
        int sI = src[e], dI = dst[e];
        float dx = pos[sI * 3 + 0] - pos[dI * 3 + 0];
        float dy = pos[sI * 3 + 1] - pos[dI * 3 + 1];
        float dz = pos[sI * 3 + 2] - pos[dI * 3 + 2];
        float d = sqrtf(dx * dx + dy * dy + dz * dz + 1e-12f);
        if (lane < G_DIM) { float u = d - lane * STEP; gbuf[wave][lane] = expf(COEFF * u * u); }
        // wave-lockstep: per-wave LDS buffers need no barrier
        float tv = b1;
        #pragma unroll
        for (int g = 0; g < G_DIM; g++) tv += gbuf[wave][g] * w1r[g];
        tv = ssp_f(tv);
        tbuf[wave][lane] = tv;
        float w = b2v;
        #pragma unroll
        for (int k = 0; k < F_DIM; k++) w += tbuf[wave][k] * w2r[k];
        w *= ccut_f(d);
        atomicAdd(&agg[dI * F_DIM + lane], x[sI * F_DIM + lane] * w);
    }
}

// ---------------- out = base + ssp(agg@cf2w + cf2b) @ lw + lb ----------------
__global__ __launch_bounds__(256) void k_update(const float* __restrict__ agg, const float* __restrict__ base,
                                                const float* cf2w, const float* cf2b,
                                                const float* lw, const float* lb,
                                                float* out, int M) {
    __shared__ float tbuf[4][H_DIM];
    int wave = threadIdx.x >> 6, lane = threadIdx.x & 63;
    int n = blockIdx.x * 4 + wave;
    float t0 = cf2b[lane], t1 = cf2b[lane + 64];
    if (n < M) {
        for (int f = 0; f < F_DIM; f++) {
            float a = agg[n * F_DIM + f];
            t0 += a * cf2w[f * H_DIM + lane];
            t1 += a * cf2w[f * H_DIM + lane + 64];
        }
    }
    tbuf[wave][lane] = ssp_f(t0);
    tbuf[wave][lane + 64] = ssp_f(t1);
    __syncthreads();
    if (n < M) {
        float o0 = lb[lane], o1 = lb[lane + 64];
        for (int k = 0; k < H_DIM; k++) {
            float tv = tbuf[wave][k];
            o0 += tv * lw[k * H_DIM + lane];
            o1 += tv * lw[k * H_DIM + lane + 64];
        }
        out[n * H_DIM + lane]      = base[n * H_DIM + lane] + o0;
        out[n * H_DIM + lane + 64] = base[n * H_DIM + lane + 64] + o1;
    }
}

// ---------------- node scores ----------------
__global__ __launch_bounds__(256) void k_scores(const float* h_local,
                                                const float* msw1, const float* msb1,
                                                const float* msw2, const float* msb2,
                                                float* scores) {
    int n = blockIdx.x * 256 + threadIdx.x;
    if (n >= N_ATOMS) return;
    float hs[S_DIM];
    for (int s = 0; s < S_DIM; s++) hs[s] = h_local[n * H_DIM + s];
    float sc = msb2[0];
    for (int j = 0; j < MH_DIM; j++) {
        float v = msb1[j];
        for (int s = 0; s < S_DIM; s++) v += hs[s] * msw1[s * MH_DIM + j];
        sc += fmaxf(v, 0.f) * msw2[j];
    }
    scores[n] = sc;
}

// ---------------- exact rank (ties -> lower index wins, matching top_k) ----------------
__global__ __launch_bounds__(256) void k_rank(const float* scores, int* rank) {
    __shared__ float s[N_ATOMS];
    for (int i = threadIdx.x; i < N_ATOMS; i += 256) s[i] = scores[i];
    __syncthreads();
    int i = blockIdx.x * 256 + threadIdx.x;
    float si = s[i];
    int r = 0;
    for (int j = 0; j < N_ATOMS; j++) {
        float sj = s[j];
        r += (sj > si) || (sj == si && j < i);
    }
    rank[i] = r;
}

// ---------------- selection, prefix, midx, m ----------------
__global__ __launch_bounds__(1024) void k_select(const float* scores, const int* rank,
                                                 int* is_m, int* invg, int* midx, float* m) {
    __shared__ int flag[N_ATOMS];
    __shared__ int bufA[N_ATOMS], bufB[N_ATOMS];
    __shared__ float kth;
    int t = threadIdx.x;
    for (int i = t; i < N_ATOMS; i += 1024) {
        int f = rank[i] < K_TOP;
        flag[i] = f;
        bufA[i] = f;
        if (rank[i] == K_TOP - 1) kth = scores[i];
    }
    __syncthreads();
    int* in = bufA;
    int* out = bufB;
    for (int d = 1; d < N_ATOMS; d <<= 1) {
        for (int i = t; i < N_ATOMS; i += 1024) out[i] = in[i] + (i >= d ? in[i - d] : 0);
        __syncthreads();
        int* tmp = in; in = out; out = tmp;
    }
    float kv = kth;
    for (int i = t; i < N_ATOMS; i += 1024) {
        int f = flag[i];
        int pos = in[i] - f;   // exclusive prefix
        is_m[i] = f;
        invg[i] = f ? pos : 0;
        if (f) midx[pos] = i;
        m[i] = sigm_f(scores[i] - kv + 1e-6f);
    }
}

// ---------------- gather h_m / pos_m ----------------
__global__ __launch_bounds__(256) void k_gather(const int* midx, const float* h_local,
                                                const float* pos, float* h_m, float* pos_m) {
    int i = blockIdx.x * 256 + threadIdx.x;  // K*H
    int k = i >> 7, c = i & 127;
    int n = midx[k];
    h_m[i] = h_local[n * H_DIM + c];
    if (c < 3) pos_m[k * 3 + c] = pos[n * 3 + c];
}

// ---------------- adjacency among selected + valid-edge list ----------------
__global__ __launch_bounds__(256) void k_adj(const int* src, const int* dst, const int* is_m,
                                             const int* invg, unsigned char* adj,
                                             int* velist, int* nve) {
    int e = blockIdx.x * 256 + threadIdx.x;
    int s = src[e], d = dst[e];
    bool valid = is_m[s] && is_m[d];
    if (valid) adj[invg[s] * K_TOP + invg[d]] = 1;
    unsigned long long mask = __ballot(valid);
    int lane = threadIdx.x & 63;
    int cnt = __popcll(mask);
    int base = 0;
    if (lane == 0 && cnt) base = atomicAdd(nve, cnt);
    base = __shfl(base, 0);
    if (valid) velist[base + __popcll(mask & ((1ull << lane) - 1))] = e;
}

// ---------------- q/k projections (S=16), 256-thread blocks ----------------
__global__ __launch_bounds__(256) void k_qk(const float* h_m, const float* wq,
                                            const float* wk, float* qm, float* km) {
    int gid = blockIdx.x * 256 + threadIdx.x;   // K*32
    int r = gid >> 5, t = gid & 31;
    const float* w = (t < 16) ? wq : wk;
    int c = t & 15;
    float acc = 0.f;
    for (int s = 0; s < S_DIM; s++) acc += h_m[r * H_DIM + s] * w[s * S_DIM + c];
    if (t < 16) qm[r * S_DIM + c] = acc; else km[r * S_DIM + c] = acc;
}

// ---------------- attention softmax -> Av mask ----------------
__global__ __launch_bounds__(256) void k_attn(const float* qm, const float* km,
                                              const unsigned char* adj, unsigned char* Av) {
    __shared__ float lrow[K_TOP];
    __shared__ float red[256];
    int i = blockIdx.x, t = threadIdx.x;
    float q[S_DIM];
    for (int s = 0; s < S_DIM; s++) q[s] = qm[i * S_DIM + s];
    for (int j = t; j < K_TOP; j += 256) {
        float acc = 0.f;
        for (int s = 0; s < S_DIM; s++) acc += q[s] * km[j * S_DIM + s];
        lrow[j] = acc * 0.25f;   // / sqrt(16)
    }
    __syncthreads();
    float mx = -1e30f;
    for (int j = t; j < K_TOP; j += 256) mx = fmaxf(mx, lrow[j]);
    red[t] = mx; __syncthreads();
    for (int o = 128; o > 0; o >>= 1) { if (t < o) red[t] = fmaxf(red[t], red[t + o]); __syncthreads(); }
    mx = red[0]; __syncthreads();
    float sum = 0.f;
    for (int j = t; j < K_TOP; j += 256) sum += expf(lrow[j] - mx);
    red[t] = sum; __syncthreads();
    for (int o = 128; o > 0; o >>= 1) { if (t < o) red[t] += red[t + o]; __syncthreads(); }
    float inv_s = 1.f / red[0];
    for (int j = t; j < K_TOP; j += 256) {
        float a = expf(lrow[j] - mx) * inv_s;
        Av[i * K_TOP + j] = (a > LAMBDA) && (!adj[i * K_TOP + j]) && (i != j);
    }
}

// ---------------- active-pair list compaction ----------------
__global__ __launch_bounds__(256) void k_plist(const unsigned char* Av, unsigned int* plist, int* npairs) {
    int idx = blockIdx.x * 256 + threadIdx.x;   // K*K
    bool act = Av[idx] != 0;
    unsigned long long mask = __ballot(act);
    int lane = threadIdx.x & 63;
    int cnt = __popcll(mask);
    int base = 0;
    if (lane == 0 && cnt) base = atomicAdd(npairs, cnt);
    base = __shfl(base, 0);
    if (act) plist[base + __popcll(mask & ((1ull << lane) - 1))] = (unsigned int)idx;
}

// ---------------- pairwise distances ----------------
__global__ __launch_bounds__(256) void k_dmat(const float* pos_m, float* dmat) {
    int idx = blockIdx.x * 256 + threadIdx.x;   // K*K
    int i = idx >> 9, j = idx & (K_TOP - 1);
    float dx = pos_m[i * 3 + 0] - pos_m[j * 3 + 0];
    float dy = pos_m[i * 3 + 1] - pos_m[j * 3 + 1];
    float dz = pos_m[i * 3 + 2] - pos_m[j * 3 + 2];
    dmat[idx] = sqrtf(dx * dx + dy * dy + dz * dz + 1e-12f);
}

// ---------------- hi = h_m@Wi, hj = h_m@Wj ----------------
__global__ __launch_bounds__(256) void k_hij(const float* h_m, const float* aw1,
                                             float* hi, float* hj) {
    int wave = threadIdx.x >> 6, lane = threadIdx.x & 63;
    int idx = blockIdx.x * 4 + wave;            // 0..1023
    int which = idx >> 9;
    int r = idx & (K_TOP - 1);
    const float* W = aw1 + which * H_DIM * H_DIM;
    float o0 = 0.f, o1 = 0.f;
    for (int k = 0; k < H_DIM; k++) {
        float hv = h_m[r * H_DIM + k];
        o0 += hv * W[k * H_DIM + lane];
        o1 += hv * W[k * H_DIM + lane + 64];
    }
    float* out = which ? hj : hi;
    out[r * H_DIM + lane] = o0;
    out[r * H_DIM + lane + 64] = o1;
}

// ---------------- per-pair attention scores over compacted list ----------------
__global__ __launch_bounds__(256) void k_score_p(const unsigned int* plist, const int* npairs,
                                                 const float* hi, const float* hj,
                                                 const float* aw1, const float* ab1,
                                                 const float* aw2, const float* ab2,
                                                 const float* dmat, float* sbuf) {
    __shared__ float gbuf[4][G_DIM];
    int t = threadIdx.x, wave = t >> 6, lane = t & 63;
    const float* wd = aw1 + 2 * H_DIM * H_DIM;
    float wdr0[G_DIM], wdr1[G_DIM];
    #pragma unroll
    for (int g = 0; g < G_DIM; g++) {
        wdr0[g] = wd[g * H_DIM + lane];
        wdr1[g] = wd[g * H_DIM + lane + 64];
    }
    float ab0 = ab1[lane], ab1v = ab1[lane + 64];
    float aw0 = aw2[lane], aw1v = aw2[lane + 64];
    float b2 = ab2[0];
    int n = npairs[0];
    int wid = blockIdx.x * 4 + wave;
    int nw = gridDim.x * 4;
    for (int p = wid; p < n; p += nw) {
        unsigned int ij = plist[p];
        int i = ij >> 9, j = ij & (K_TOP - 1);
        float dd = dmat[ij];
        if (lane < G_DIM) { float u = dd - lane * STEP; gbuf[wave][lane] = expf(COEFF * u * u); }
        float v0 = hi[i * H_DIM + lane] + hj[j * H_DIM + lane] + ab0;
        float v1 = hi[i * H_DIM + lane + 64] + hj[j * H_DIM + lane + 64] + ab1v;
        #pragma unroll
        for (int g = 0; g < G_DIM; g++) {
            float gv = gbuf[wave][g];
            v0 += gv * wdr0[g];
            v1 += gv * wdr1[g];
        }
        float pv = fmaxf(v0, 0.f) * aw0 + fmaxf(v1, 0.f) * aw1v;
        for (int o = 1; o < 64; o <<= 1) pv += __shfl_xor(pv, o);
        if (lane == 0) sbuf[ij] = pv + b2;
    }
}

// ---------------- row softmax (Av-guarded) -> decay ----------------
__global__ __launch_bounds__(256) void k_decay(const float* sbuf, const unsigned char* Av, float* decay) {
    __shared__ float srow[K_TOP];
    __shared__ float red[256];
    int i = blockIdx.x, t = threadIdx.x;
    for (int j = t; j < K_TOP; j += 256)
        srow[j] = Av[i * K_TOP + j] ? sbuf[i * K_TOP + j] : -1e9f;
    __syncthreads();
    float mx = -1e30f;
    for (int j = t; j < K_TOP; j += 256) mx = fmaxf(mx, srow[j]);
    red[t] = mx; __syncthreads();
    for (int o = 128; o > 0; o >>= 1) { if (t < o) red[t] = fmaxf(red[t], red[t + o]); __syncthreads(); }
    mx = red[0]; __syncthreads();
    float sum = 0.f;
    for (int j = t; j < K_TOP; j += 256) sum += (srow[j] > -5e8f) ? expf(srow[j] - mx) : 0.f;
    red[t] = sum; __syncthreads();
    for (int o = 128; o > 0; o >>= 1) { if (t < o) red[t] += red[t + o]; __syncthreads(); }
    float s_total = red[0];
    float inv_s = (s_total > 0.f) ? 1.f / s_total : 0.f;
    for (int j = t; j < K_TOP; j += 256)
        decay[i * K_TOP + j] = (srow[j] > -5e8f) ? expf(srow[j] - mx) * inv_s : 0.f;
}

// ---------------- agg_d over compacted pair list ----------------
__global__ __launch_bounds__(256) void k_aggd_p(const unsigned int* plist, const int* npairs,
                                                const float* xm, const float* dmat, const float* decay,
                                                const float* mw1, const float* mb1,
                                                const float* mw2, const float* mb2,
                                                float* agg_m) {
    __shared__ float gbuf[4][G_DIM], tbuf[4][F_DIM];
    int t = threadIdx.x, wave = t >> 6, lane = t & 63;
    float w1r[G_DIM], w2r[F_DIM];
    #pragma unroll
    for (int g = 0; g < G_DIM; g++) w1r[g] = mw1[g * F_DIM + lane];
    #pragma unroll
    for (int k = 0; k < F_DIM; k++) w2r[k] = mw2[k * F_DIM + lane];
    float b1 = mb1[lane], b2v = mb2[lane];
    int n = npairs[0];
    int wid = blockIdx.x * 4 + wave;
    int nw = gridDim.x * 4;
    for (int p = wid; p < n; p += nw) {
        unsigned int ij = plist[p];
        int i = ij >> 9, j = ij & (K_TOP - 1);
        float dd = dmat[ij];
        float dec = decay[ij];
        if (lane < G_DIM) { float u = dd - lane * STEP; gbuf[wave][lane] = expf(COEFF * u * u) * dec; }
        float tv = b1;
        #pragma unroll
        for (int g = 0; g < G_DIM; g++) tv += gbuf[wave][g] * w1r[g];
        tv = ssp_f(tv);
        tbuf[wave][lane] = tv;
        float w = b2v;
        #pragma unroll
        for (int k = 0; k < F_DIM; k++) w += tbuf[wave][k] * w2r[k];
        atomicAdd(&agg_m[j * F_DIM + lane], xm[i * F_DIM + lane] * w * ccut_f(dd));
    }
}

// ---------------- valid-edge filter over compacted edge list ----------------
__global__ __launch_bounds__(256) void k_aggs_p(const int* velist, const int* nve,
                                                const float* pos_m, const int* src, const int* dst,
                                                const int* invg, const float* xm,
                                                const float* mw1, const float* mb1,
                                                const float* mw2, const float* mb2,
                                                float* agg_m) {
    __shared__ float gbuf[4][G_DIM], tbuf[4][F_DIM];
    int t = threadIdx.x, wave = t >> 6, lane = t & 63;
    float w1r[G_DIM], w2r[F_DIM];
    #pragma unroll
    for (int g = 0; g < G_DIM; g++) w1r[g] = mw1[g * F_DIM + lane];
    #pragma unroll
    for (int k = 0; k < F_DIM; k++) w2r[k] = mw2[k * F_DIM + lane];
    float b1 = mb1[lane], b2v = mb2[lane];
    int n = nve[0];
    int wid = blockIdx.x * 4 + wave;
    int nw = gridDim.x * 4;
    for (int p = wid; p < n; p += nw) {
        int e = velist[p];
        int sm = invg[src[e]];
        int dm = invg[dst[e]];
        float dx = pos_m[sm * 3 + 0] - pos_m[dm * 3 + 0];
        float dy = pos_m[sm * 3 + 1] - pos_m[dm * 3 + 1];
        float dz = pos_m[sm * 3 + 2] - pos_m[dm * 3 + 2];
        float d = sqrtf(dx * dx + dy * dy + dz * dz + 1e-12f);
        if (lane < G_DIM) { float u = d - lane * STEP; gbuf[wave][lane] = expf(COEFF * u * u); }
        float tv = b1;
        #pragma unroll
        for (int g = 0; g < G_DIM; g++) tv += gbuf[wave][g] * w1r[g];
        tv = ssp_f(tv);
        tbuf[wave][lane] = tv;
        float w = b2v;
        #pragma unroll
        for (int k = 0; k < F_DIM; k++) w += tbuf[wave][k] * w2r[k];
        atomicAdd(&agg_m[dm * F_DIM + lane], xm[sm * F_DIM + lane] * w * ccut_f(d));
    }
}

// ---------------- blend ----------------
__global__ __launch_bounds__(256) void k_blend(const float* h_local, const float* h_hier,
                                               const int* is_m, const int* invg, const float* m,
                                               float* h_out) {
    int idx = blockIdx.x * 256 + threadIdx.x;   // N*H
    int n = idx >> 7, c = idx & 127;
    float mm = m[n];
    float hh = is_m[n] ? h_hier[invg[n] * H_DIM + c] : 0.f;
    h_out[idx] = (1.f - mm) * h_local[idx] + mm * hh;
}

// ---------------- parallel segment-sum pooling ----------------
__global__ __launch_bounds__(256) void k_pool(const float* __restrict__ h, const int* __restrict__ batch,
                                              float* pooled) {
    int c = threadIdx.x & 127, a = threadIdx.x >> 7;
    int n0 = blockIdx.x * 64;
    float acc = 0.f;
    int cur = batch[n0 + a];
    for (int i = a; i < 64; i += 2) {
        int n = n0 + i;
        int b = batch[n];
        if (b != cur) { atomicAdd(&pooled[cur * H_DIM + c], acc); acc = 0.f; cur = b; }
        acc += h[n * H_DIM + c];
    }
    atomicAdd(&pooled[cur * H_DIM + c], acc);
}

// ---------------- predict MLP (dual-dtype output) ----------------
__global__ __launch_bounds__(128) void k_pred2(const float* pooled,
                                               const float* w1, const float* b1,
                                               const float* w2, const float* b2,
                                               void* outv, const int* flag) {
    __shared__ float c64[64];
    int b = blockIdx.x, t = threadIdx.x;
    if (t < 64) {
        float v = b1[t];
        for (int k = 0; k < H_DIM; k++) v += pooled[b * H_DIM + k] * w1[k * 64 + t];
        c64[t] = v * sigm_f(v);   // silu
    }
    __syncthreads();
    if (t == 0) {
        float o = b2[0];
        for (int k = 0; k < 64; k++) o += c64[k] * w2[k];
        if (flag[0]) ((float*)outv)[b] = o;
        else ((__hip_bfloat16*)outv)[b] = __float2bfloat16(o);
    }
}

extern "C" void kernel_launch(void* const* d_in, const int* in_sizes, int n_in,
                              void* d_out, int out_size, void* d_ws, size_t ws_size,
                              hipStream_t stream) {
    (void)n_in; (void)out_size; (void)ws_size;
    const int* atoms = (const int*)d_in[0];
    const int* src = (const int*)d_in[2];
    const int* dst = (const int*)d_in[3];
    const int* batch = (const int*)d_in[4];

    // -------- workspace carve (fp32) --------
    float* W = (float*)d_ws;
    int* dflag = (int*)W; W += 16;     // dtype flag (aligned pad)
    int* counters = (int*)W; W += 16;  // [0]=npairs, [1]=nve

    // fp32-converted copies of all float inputs (fused single conversion kernel)
    static const int fidx[25] = {1,5,6,7,8,9,10,11,12,13,14,15,16,17,18,19,20,21,22,23,24,25,26,27,28};
    float* fin[29];
    ConvArgs ca;
    float* convBase = W;
    int off = 0;
    for (int q = 0; q < 25; q++) {
        int i = fidx[q];
        ca.p[q] = d_in[i];
        ca.off[q] = off;
        fin[i] = convBase + off;
        off += in_sizes[i];
    }
    ca.off[25] = off;
    W += off;

    k_detect<<<1, 256, 0, stream>>>((const unsigned short*)d_in[5], in_sizes[5], dflag);
    k_convert_all<<<(off + 255) / 256, 256, 0, stream>>>(ca, convBase, dflag);

    const float* posf = fin[1];
    const float* embf = fin[5];

    float* h      = W; W += N_ATOMS * H_DIM;
    float* h_loc  = W; W += N_ATOMS * H_DIM;
    float* xbuf   = W; W += N_ATOMS * F_DIM;
    float* aggbuf = W; W += N_ATOMS * F_DIM;
    float* scores = W; W += N_ATOMS;
    float* mbuf   = W; W += N_ATOMS;
    float* h_m    = W; W += K_TOP * H_DIM;
    float* pos_m  = W; W += K_TOP * 3;
    float* xm     = W; W += K_TOP * F_DIM;
    float* qm     = W; W += K_TOP * S_DIM;
    float* km     = W; W += K_TOP * S_DIM;
    float* dmat   = W; W += K_TOP * K_TOP;
    float* decay  = W; W += K_TOP * K_TOP;
    float* sbuf   = W; W += K_TOP * K_TOP;
    float* hi     = W; W += K_TOP * H_DIM;
    float* hj     = W; W += K_TOP * H_DIM;
    float* agg_m  = W; W += K_TOP * F_DIM;
    float* h_hier = W; W += K_TOP * H_DIM;
    float* pooled = W; W += B_BATCH * H_DIM;
    int* rankb  = (int*)W; W += N_ATOMS;
    int* is_m   = (int*)W; W += N_ATOMS;
    int* invg   = (int*)W; W += N_ATOMS;
    int* midx   = (int*)W; W += K_TOP;
    unsigned int* plist = (unsigned int*)W; W += K_TOP * K_TOP;
    int* velist = (int*)W; W += E_EDGES;
    unsigned char* adj = (unsigned char*)W; W += (K_TOP * K_TOP) / 4;
    unsigned char* Av  = (unsigned char*)W; W += (K_TOP * K_TOP) / 4;

    k_embed<<<(N_ATOMS * H_DIM) / 256, 256, 0, stream>>>(atoms, embf, h);

    for (int l = 0; l < L_LAYERS; l++) {
        const float* mw1 = fin[6]  + l * G_DIM * F_DIM;
        const float* mb1 = fin[7]  + l * F_DIM;
        const float* mw2 = fin[8]  + l * F_DIM * F_DIM;
        const float* mb2 = fin[9]  + l * F_DIM;
        const float* cf1 = fin[10] + l * H_DIM * F_DIM;
        const float* cf2w = fin[11] + l * F_DIM * H_DIM;
        const float* cf2b = fin[12] + l * H_DIM;
        const float* lw  = fin[13] + l * H_DIM * H_DIM;
        const float* lb  = fin[14] + l * H_DIM;
        const float* aw1 = fin[15] + l * (2 * H_DIM + G_DIM) * H_DIM;
        const float* ab1 = fin[16] + l * H_DIM;
        const float* aw2 = fin[17] + l * H_DIM;
        const float* ab2 = fin[18] + l;
        const float* msw1 = fin[19] + l * S_DIM * MH_DIM;
        const float* msb1 = fin[20] + l * MH_DIM;
        const float* msw2 = fin[21] + l * MH_DIM;
        const float* msb2 = fin[22] + l;
        const float* wq  = fin[23] + l * S_DIM * S_DIM;
        const float* wk  = fin[24] + l * S_DIM * S_DIM;

        k_x<<<N_ATOMS / 4, 256, 0, stream>>>(h, cf1, xbuf, N_ATOMS);
        (void)hipMemsetAsync(aggbuf, 0, N_ATOMS * F_DIM * sizeof(float), stream);
        k_edge<<<E_EDGES / (4 * EPW), 256, 0, stream>>>(posf, src, dst, xbuf, mw1, mb1, mw2, mb2, aggbuf);
        k_update<<<N_ATOMS / 4, 256, 0, stream>>>(aggbuf, h, cf2w, cf2b, lw, lb, h_loc, N_ATOMS);
        k_scores<<<N_ATOMS / 256, 256, 0, stream>>>(h_loc, msw1, msb1, msw2, msb2, scores);
        k_rank<<<N_ATOMS / 256, 256, 0, stream>>>(scores, rankb);
        k_select<<<1, 1024, 0, stream>>>(scores, rankb, is_m, invg, midx, mbuf);
        k_gather<<<(K_TOP * H_DIM) / 256, 256, 0, stream>>>(midx, h_loc, posf, h_m, pos_m);
        k_x<<<K_TOP / 4, 256, 0, stream>>>(h_m, cf1, xm, K_TOP);
        (void)hipMemsetAsync(adj, 0, K_TOP * K_TOP, stream);
        (void)hipMemsetAsync(counters, 0, 2 * sizeof(int), stream);
        k_adj<<<E_EDGES / 256, 256, 0, stream>>>(src, dst, is_m, invg, adj, velist, counters + 1);
        k_qk<<<(K_TOP * 32) / 256, 256, 0, stream>>>(h_m, wq, wk, qm, km);
        k_attn<<<K_TOP, 256, 0, stream>>>(qm, km, adj, Av);
        k_plist<<<(K_TOP * K_TOP) / 256, 256, 0, stream>>>(Av, plist, counters);
        k_dmat<<<(K_TOP * K_TOP) / 256, 256, 0, stream>>>(pos_m, dmat);
        k_hij<<<(2 * K_TOP) / 4, 256, 0, stream>>>(h_m, aw1, hi, hj);
        k_score_p<<<1024, 256, 0, stream>>>(plist, counters, hi, hj, aw1, ab1, aw2, ab2, dmat, sbuf);
        k_decay<<<K_TOP, 256, 0, stream>>>(sbuf, Av, decay);
        (void)hipMemsetAsync(agg_m, 0, K_TOP * F_DIM * sizeof(float), stream);
        k_aggd_p<<<1024, 256, 0, stream>>>(plist, counters, xm, dmat, decay, mw1, mb1, mw2, mb2, agg_m);
        k_aggs_p<<<256, 256, 0, stream>>>(velist, counters + 1, pos_m, src, dst, invg, xm,
                                          mw1, mb1, mw2, mb2, agg_m);
        k_update<<<K_TOP / 4, 256, 0, stream>>>(agg_m, h_m, cf2w, cf2b, lw, lb, h_hier, K_TOP);
        k_blend<<<(N_ATOMS * H_DIM) / 256, 256, 0, stream>>>(h_loc, h_hier, is_m, invg, mbuf, h);
    }

    (void)hipMemsetAsync(pooled, 0, B_BATCH * H_DIM * sizeof(float), stream);
    k_pool<<<N_ATOMS / 64, 256, 0, stream>>>(h, batch, pooled);
    k_pred2<<<B_BATCH, 128, 0, stream>>>(pooled, fin[25], fin[26], fin[27], fin[28], d_out, dflag);
}

// Round 8
// 793.468 us; speedup vs baseline: 1.2532x; 1.0715x over previous
//
#include <hip/hip_runtime.h>
#include <hip/hip_bf16.h>
#include <math.h>

#define N_ATOMS 2048
#define E_EDGES 65536
#define B_BATCH 8
#define H_DIM 128
#define G_DIM 50
#define F_DIM 64
#define S_DIM 16
#define MH_DIM 32
#define K_TOP 512
#define L_LAYERS 2
#define EPW2 16         // sorted edges per wave in k_edge_s
#define PCHUNK 32       // pairs per wave-chunk in k_aggd_p2

static constexpr float STEP   = 10.0f / 49.0f;          // OFFSET spacing
static constexpr float COEFF  = -12.005f;               // -0.5/STEP^2
static constexpr float PI10   = 0.31415926535897931f;   // pi/CUTOFF
static constexpr float LN2    = 0.69314718055994531f;
static constexpr float LAMBDA = 0.002f;

#define DEV static __device__ __forceinline__

DEV float ssp_f(float x) { return fmaxf(x, 0.f) + log1pf(expf(-fabsf(x))) - LN2; }
DEV float ccut_f(float d) { return 0.5f * (cosf(d * PI10) + 1.f); }
DEV float sigm_f(float x) { return 1.f / (1.f + expf(-x)); }

// ---------------- dtype detect ----------------
__global__ __launch_bounds__(256) void k_detect(const unsigned short* raw, int n, int* flag) {
    __shared__ int any;
    if (threadIdx.x == 0) any = 0;
    __syncthreads();
    for (int i = threadIdx.x; i < n; i += 256) {
        unsigned int bits = ((unsigned int)raw[i]) << 16;
        float f = __uint_as_float(bits);
        if (!(fabsf(f) <= 1e10f)) any = 1;
    }
    __syncthreads();
    if (threadIdx.x == 0) flag[0] = any;
}

// ---------------- fused convert ----------------
struct ConvArgs {
    const void* p[25];
    int off[26];
};

__global__ __launch_bounds__(256) void k_convert_all(ConvArgs a, float* dst, const int* flag) {
    int i = blockIdx.x * 256 + threadIdx.x;
    int total = a.off[25];
    if (i >= total) return;
    int seg = 0;
    while (i >= a.off[seg + 1]) seg++;
    int k = i - a.off[seg];
    if (flag[0]) {
        dst[i] = ((const float*)a.p[seg])[k];
    } else {
        unsigned int bits = ((unsigned int)((const unsigned short*)a.p[seg])[k]) << 16;
        dst[i] = __uint_as_float(bits);
    }
}

// ---------------- edge counting-sort by dst (once; src/dst static) ----------------
__global__ __launch_bounds__(256) void k_ehist(const int* dst, int* hist) {
    int e = blockIdx.x * 256 + threadIdx.x;
    atomicAdd(&hist[dst[e]], 1);
}

// scan 2048 ints -> exclusive ebase + working copy ecur
__global__ __launch_bounds__(1024) void k_escan(const int* hist, int* ebase, int* ecur) {
    __shared__ int bufA[N_ATOMS], bufB[N_ATOMS];
    int t = threadIdx.x;
    for (int i = t; i < N_ATOMS; i += 1024) bufA[i] = hist[i];
    __syncthreads();
    int* in = bufA;
    int* out = bufB;
    for (int d = 1; d < N_ATOMS; d <<= 1) {
        for (int i = t; i < N_ATOMS; i += 1024) out[i] = in[i] + (i >= d ? in[i - d] : 0);
        __syncthreads();
        int* tmp = in; in = out; out = tmp;
    }
    for (int i = t; i < N_ATOMS; i += 1024) {
        int ex = in[i] - hist[i];
        ebase[i] = ex;
        ecur[i] = ex;
    }
}

__global__ __launch_bounds__(256) void k_escatter(const int* dst, int* ecur, int* esorted) {
    int e = blockIdx.x * 256 + threadIdx.x;
    int pos = atomicAdd(&ecur[dst[e]], 1);
    esorted[pos] = e;
}

// ---------------- embedding ----------------
__global__ __launch_bounds__(256) void k_embed(const int* atoms, const float* emb, float* h) {
    int i = blockIdx.x * 256 + threadIdx.x;
    int n = i >> 7, c = i & 127;
    h[i] = emb[atoms[n] * H_DIM + c];
}

// ---------------- x = h @ cf1 ----------------
__global__ __launch_bounds__(256) void k_x(const float* __restrict__ h, const float* __restrict__ cf1,
                                           float* __restrict__ x, int M) {
    int wave = threadIdx.x >> 6, lane = threadIdx.x & 63;
    int n = blockIdx.x * 4 + wave;
    if (n >= M) return;
    float acc = 0.f;
    for (int k = 0; k < H_DIM; k++) acc += h[n * H_DIM + k] * cf1[k * F_DIM + lane];
    x[n * F_DIM + lane] = acc;
}

// ---------------- edge filter over dst-sorted edges, run-accumulated ----------------
__global__ __launch_bounds__(256) void k_edge_s(const int* esorted, const float* pos,
                                                const int* src, const int* dst, const float* x,
                                                const float* mw1, const float* mb1,
                                                const float* mw2, const float* mb2,
                                                float* agg) {
    __shared__ float gbuf[4][G_DIM], tbuf[4][F_DIM];
    int t = threadIdx.x, wave = t >> 6, lane = t & 63;
    float w1r[G_DIM], w2r[F_DIM];
    #pragma unroll
    for (int g = 0; g < G_DIM; g++) w1r[g] = mw1[g * F_DIM + lane];
    #pragma unroll
    for (int k = 0; k < F_DIM; k++) w2r[k] = mw2[k * F_DIM + lane];
    float b1 = mb1[lane], b2v = mb2[lane];
    int p0 = (blockIdx.x * 4 + wave) * EPW2;
    int curDst = -1;
    float acc = 0.f;
    for (int ee = 0; ee < EPW2; ee++) {
        int e = esorted[p0 + ee];
        int sI = src[e], dI = dst[e];
        float dx = pos[sI * 3 + 0] - pos[dI * 3 + 0];
        float dy = pos[sI * 3 + 1] - pos[dI * 3 + 1];
        float dz = pos[sI * 3 + 2] - pos[dI * 3 + 2];
        float d = sqrtf(dx * dx + dy * dy + dz * dz + 1e-12f);
        if (lane < G_DIM) { float u = d - lane * STEP; gbuf[wave][lane] = expf(COEFF * u * u); }
        float tv = b1;
        #pragma unroll
        for (int g = 0; g < G_DIM; g++) tv += gbuf[wave][g] * w1r[g];
        tv = ssp_f(tv);
        tbuf[wave][lane] = tv;
        float w = b2v;
        #pragma unroll
        for (int k = 0; k < F_DIM; k++) w += tbuf[wave][k] * w2r[k];
        w *= ccut_f(d);
        float contrib = x[sI * F_DIM + lane] * w;
        if (dI != curDst) {
            if (curDst >= 0) atomicAdd(&agg[curDst * F_DIM + lane], acc);
            acc = 0.f;
            curDst = dI;
        }
        acc += contrib;
    }
    if (curDst >= 0) atomicAdd(&agg[curDst * F_DIM + lane], acc);
}

// ---------------- out = base + ssp(agg@cf2w + cf2b) @ lw + lb ----------------
__global__ __launch_bounds__(256) void k_update(const float* __restrict__ agg, const float* __restrict__ base,
                                                const float* cf2w, const float* cf2b,
                                                const float* lw, const float* lb,
                                                float* out, int M) {
    __shared__ float tbuf[4][H_DIM];
    int wave = threadIdx.x >> 6, lane = threadIdx.x & 63;
    int n = blockIdx.x * 4 + wave;
    float t0 = cf2b[lane], t1 = cf2b[lane + 64];
    if (n < M) {
        for (int f = 0; f < F_DIM; f++) {
            float a = agg[n * F_DIM + f];
            t0 += a * cf2w[f * H_DIM + lane];
            t1 += a * cf2w[f * H_DIM + lane + 64];
        }
    }
    tbuf[wave][lane] = ssp_f(t0);
    tbuf[wave][lane + 64] = ssp_f(t1);
    __syncthreads();
    if (n < M) {
        float o0 = lb[lane], o1 = lb[lane + 64];
        for (int k = 0; k < H_DIM; k++) {
            float tv = tbuf[wave][k];
            o0 += tv * lw[k * H_DIM + lane];
            o1 += tv * lw[k * H_DIM + lane + 64];
        }
        out[n * H_DIM + lane]      = base[n * H_DIM + lane] + o0;
        out[n * H_DIM + lane + 64] = base[n * H_DIM + lane + 64] + o1;
    }
}

// ---------------- node scores ----------------
__global__ __launch_bounds__(256) void k_scores(const float* h_local,
                                                const float* msw1, const float* msb1,
                                                const float* msw2, const float* msb2,
                                                float* scores) {
    int n = blockIdx.x * 256 + threadIdx.x;
    if (n >= N_ATOMS) return;
    float hs[S_DIM];
    for (int s = 0; s < S_DIM; s++) hs[s] = h_local[n * H_DIM + s];
    float sc = msb2[0];
    for (int j = 0; j < MH_DIM; j++) {
        float v = msb1[j];
        for (int s = 0; s < S_DIM; s++) v += hs[s] * msw1[s * MH_DIM + j];
        sc += fmaxf(v, 0.f) * msw2[j];
    }
    scores[n] = sc;
}

// ---------------- exact rank ----------------
__global__ __launch_bounds__(256) void k_rank(const float* scores, int* rank) {
    __shared__ float s[N_ATOMS];
    for (int i = threadIdx.x; i < N_ATOMS; i += 256) s[i] = scores[i];
    __syncthreads();
    int i = blockIdx.x * 256 + threadIdx.x;
    float si = s[i];
    int r = 0;
    for (int j = 0; j < N_ATOMS; j++) {
        float sj = s[j];
        r += (sj > si) || (sj == si && j < i);
    }
    rank[i] = r;
}

// ---------------- selection, prefix, midx, m ----------------
__global__ __launch_bounds__(1024) void k_select(const float* scores, const int* rank,
                                                 int* is_m, int* invg, int* midx, float* m) {
    __shared__ int flag[N_ATOMS];
    __shared__ int bufA[N_ATOMS], bufB[N_ATOMS];
    __shared__ float kth;
    int t = threadIdx.x;
    for (int i = t; i < N_ATOMS; i += 1024) {
        int f = rank[i] < K_TOP;
        flag[i] = f;
        bufA[i] = f;
        if (rank[i] == K_TOP - 1) kth = scores[i];
    }
    __syncthreads();
    int* in = bufA;
    int* out = bufB;
    for (int d = 1; d < N_ATOMS; d <<= 1) {
        for (int i = t; i < N_ATOMS; i += 1024) out[i] = in[i] + (i >= d ? in[i - d] : 0);
        __syncthreads();
        int* tmp = in; in = out; out = tmp;
    }
    float kv = kth;
    for (int i = t; i < N_ATOMS; i += 1024) {
        int f = flag[i];
        int pos = in[i] - f;
        is_m[i] = f;
        invg[i] = f ? pos : 0;
        if (f) midx[pos] = i;
        m[i] = sigm_f(scores[i] - kv + 1e-6f);
    }
}

// ---------------- gather h_m / pos_m ----------------
__global__ __launch_bounds__(256) void k_gather(const int* midx, const float* h_local,
                                                const float* pos, float* h_m, float* pos_m) {
    int i = blockIdx.x * 256 + threadIdx.x;
    int k = i >> 7, c = i & 127;
    int n = midx[k];
    h_m[i] = h_local[n * H_DIM + c];
    if (c < 3) pos_m[k * 3 + c] = pos[n * 3 + c];
}

// ---------------- adjacency + valid-edge list ----------------
__global__ __launch_bounds__(256) void k_adj(const int* src, const int* dst, const int* is_m,
                                             const int* invg, unsigned char* adj,
                                             int* velist, int* nve) {
    int e = blockIdx.x * 256 + threadIdx.x;
    int s = src[e], d = dst[e];
    bool valid = is_m[s] && is_m[d];
    if (valid) adj[invg[s] * K_TOP + invg[d]] = 1;
    unsigned long long mask = __ballot(valid);
    int lane = threadIdx.x & 63;
    int cnt = __popcll(mask);
    int base = 0;
    if (lane == 0 && cnt) base = atomicAdd(nve, cnt);
    base = __shfl(base, 0);
    if (valid) velist[base + __popcll(mask & ((1ull << lane) - 1))] = e;
}

// ---------------- q/k projections ----------------
__global__ __launch_bounds__(256) void k_qk(const float* h_m, const float* wq,
                                            const float* wk, float* qm, float* km) {
    int gid = blockIdx.x * 256 + threadIdx.x;
    int r = gid >> 5, t = gid & 31;
    const float* w = (t < 16) ? wq : wk;
    int c = t & 15;
    float acc = 0.f;
    for (int s = 0; s < S_DIM; s++) acc += h_m[r * H_DIM + s] * w[s * S_DIM + c];
    if (t < 16) qm[r * S_DIM + c] = acc; else km[r * S_DIM + c] = acc;
}

// ---------------- attention softmax -> Av mask ----------------
__global__ __launch_bounds__(256) void k_attn(const float* qm, const float* km,
                                              const unsigned char* adj, unsigned char* Av) {
    __shared__ float lrow[K_TOP];
    __shared__ float red[256];
    int i = blockIdx.x, t = threadIdx.x;
    float q[S_DIM];
    for (int s = 0; s < S_DIM; s++) q[s] = qm[i * S_DIM + s];
    for (int j = t; j < K_TOP; j += 256) {
        float acc = 0.f;
        for (int s = 0; s < S_DIM; s++) acc += q[s] * km[j * S_DIM + s];
        lrow[j] = acc * 0.25f;
    }
    __syncthreads();
    float mx = -1e30f;
    for (int j = t; j < K_TOP; j += 256) mx = fmaxf(mx, lrow[j]);
    red[t] = mx; __syncthreads();
    for (int o = 128; o > 0; o >>= 1) { if (t < o) red[t] = fmaxf(red[t], red[t + o]); __syncthreads(); }
    mx = red[0]; __syncthreads();
    float sum = 0.f;
    for (int j = t; j < K_TOP; j += 256) sum += expf(lrow[j] - mx);
    red[t] = sum; __syncthreads();
    for (int o = 128; o > 0; o >>= 1) { if (t < o) red[t] += red[t + o]; __syncthreads(); }
    float inv_s = 1.f / red[0];
    for (int j = t; j < K_TOP; j += 256) {
        float a = expf(lrow[j] - mx) * inv_s;
        Av[i * K_TOP + j] = (a > LAMBDA) && (!adj[i * K_TOP + j]) && (i != j);
    }
}

// ---------------- deterministic j-major pair compaction ----------------
// pass 1: per-block active counts (idx = j*K + i traversal)
__global__ __launch_bounds__(256) void k_pcount(const unsigned char* Av, int* bcount) {
    __shared__ int wsum[4];
    int idx = blockIdx.x * 256 + threadIdx.x;
    int j = idx >> 9, i = idx & (K_TOP - 1);
    bool act = Av[i * K_TOP + j] != 0;
    unsigned long long mask = __ballot(act);
    int lane = threadIdx.x & 63, wave = threadIdx.x >> 6;
    if (lane == 0) wsum[wave] = __popcll(mask);
    __syncthreads();
    if (threadIdx.x == 0) bcount[blockIdx.x] = wsum[0] + wsum[1] + wsum[2] + wsum[3];
}

// pass 2: scan 1024 block counts -> exclusive offsets + total
__global__ __launch_bounds__(1024) void k_pscan(const int* bcount, int* boffset, int* total) {
    __shared__ int bufA[1024], bufB[1024];
    int t = threadIdx.x;
    bufA[t] = bcount[t];
    __syncthreads();
    int* in = bufA;
    int* out = bufB;
    for (int d = 1; d < 1024; d <<= 1) {
        out[t] = in[t] + (t >= d ? in[t - d] : 0);
        __syncthreads();
        int* tmp = in; in = out; out = tmp;
    }
    boffset[t] = in[t] - bcount[t];
    if (t == 1023) total[0] = in[1023];
}

// pass 3: ordered scatter, key = (j<<9)|i
__global__ __launch_bounds__(256) void k_pscatter(const unsigned char* Av, const int* boffset,
                                                  unsigned int* plist) {
    __shared__ int wsum[4], woff[4];
    int idx = blockIdx.x * 256 + threadIdx.x;
    int j = idx >> 9, i = idx & (K_TOP - 1);
    bool act = Av[i * K_TOP + j] != 0;
    unsigned long long mask = __ballot(act);
    int lane = threadIdx.x & 63, wave = threadIdx.x >> 6;
    if (lane == 0) wsum[wave] = __popcll(mask);
    __syncthreads();
    if (threadIdx.x == 0) {
        int s = 0;
        for (int w = 0; w < 4; w++) { woff[w] = s; s += wsum[w]; }
    }
    __syncthreads();
    if (act) {
        int pos = boffset[blockIdx.x] + woff[wave] + __popcll(mask & ((1ull << lane) - 1));
        plist[pos] = ((unsigned int)j << 9) | (unsigned int)i;
    }
}

// ---------------- pairwise distances ----------------
__global__ __launch_bounds__(256) void k_dmat(const float* pos_m, float* dmat) {
    int idx = blockIdx.x * 256 + threadIdx.x;
    int i = idx >> 9, j = idx & (K_TOP - 1);
    float dx = pos_m[i * 3 + 0] - pos_m[j * 3 + 0];
    float dy = pos_m[i * 3 + 1] - pos_m[j * 3 + 1];
    float dz = pos_m[i * 3 + 2] - pos_m[j * 3 + 2];
    dmat[idx] = sqrtf(dx * dx + dy * dy + dz * dz + 1e-12f);
}

// ---------------- hi = h_m@Wi, hj = h_m@Wj ----------------
__global__ __launch_bounds__(256) void k_hij(const float* h_m, const float* aw1,
                                             float* hi, float* hj) {
    int wave = threadIdx.x >> 6, lane = threadIdx.x & 63;
    int idx = blockIdx.x * 4 + wave;
    int which = idx >> 9;
    int r = idx & (K_TOP - 1);
    const float* W = aw1 + which * H_DIM * H_DIM;
    float o0 = 0.f, o1 = 0.f;
    for (int k = 0; k < H_DIM; k++) {
        float hv = h_m[r * H_DIM + k];
        o0 += hv * W[k * H_DIM + lane];
        o1 += hv * W[k * H_DIM + lane + 64];
    }
    float* out = which ? hj : hi;
    out[r * H_DIM + lane] = o0;
    out[r * H_DIM + lane + 64] = o1;
}

// ---------------- per-pair attention scores over j-major list ----------------
__global__ __launch_bounds__(256) void k_score_p(const unsigned int* plist, const int* npairs,
                                                 const float* hi, const float* hj,
                                                 const float* aw1, const float* ab1,
                                                 const float* aw2, const float* ab2,
                                                 const float* dmat, float* sbuf) {
    __shared__ float gbuf[4][G_DIM];
    int t = threadIdx.x, wave = t >> 6, lane = t & 63;
    const float* wd = aw1 + 2 * H_DIM * H_DIM;
    float wdr0[G_DIM], wdr1[G_DIM];
    #pragma unroll
    for (int g = 0; g < G_DIM; g++) {
        wdr0[g] = wd[g * H_DIM + lane];
        wdr1[g] = wd[g * H_DIM + lane + 64];
    }
    float ab0 = ab1[lane], ab1v = ab1[lane + 64];
    float aw0 = aw2[lane], aw1v = aw2[lane + 64];
    float b2 = ab2[0];
    int n = npairs[0];
    int wid = blockIdx.x * 4 + wave;
    int nw = gridDim.x * 4;
    for (int p = wid; p < n; p += nw) {
        unsigned int key = plist[p];
        int j = key >> 9, i = key & (K_TOP - 1);
        int ij = i * K_TOP + j;
        float dd = dmat[ij];
        if (lane < G_DIM) { float u = dd - lane * STEP; gbuf[wave][lane] = expf(COEFF * u * u); }
        float v0 = hi[i * H_DIM + lane] + hj[j * H_DIM + lane] + ab0;
        float v1 = hi[i * H_DIM + lane + 64] + hj[j * H_DIM + lane + 64] + ab1v;
        #pragma unroll
        for (int g = 0; g < G_DIM; g++) {
            float gv = gbuf[wave][g];
            v0 += gv * wdr0[g];
            v1 += gv * wdr1[g];
        }
        float pv = fmaxf(v0, 0.f) * aw0 + fmaxf(v1, 0.f) * aw1v;
        for (int o = 1; o < 64; o <<= 1) pv += __shfl_xor(pv, o);
        if (lane == 0) sbuf[ij] = pv + b2;
    }
}

// ---------------- row softmax (Av-guarded) -> decay ----------------
__global__ __launch_bounds__(256) void k_decay(const float* sbuf, const unsigned char* Av, float* decay) {
    __shared__ float srow[K_TOP];
    __shared__ float red[256];
    int i = blockIdx.x, t = threadIdx.x;
    for (int j = t; j < K_TOP; j += 256)
        srow[j] = Av[i * K_TOP + j] ? sbuf[i * K_TOP + j] : -1e9f;
    __syncthreads();
    float mx = -1e30f;
    for (int j = t; j < K_TOP; j += 256) mx = fmaxf(mx, srow[j]);
    red[t] = mx; __syncthreads();
    for (int o = 128; o > 0; o >>= 1) { if (t < o) red[t] = fmaxf(red[t], red[t + o]); __syncthreads(); }
    mx = red[0]; __syncthreads();
    float sum = 0.f;
    for (int j = t; j < K_TOP; j += 256) sum += (srow[j] > -5e8f) ? expf(srow[j] - mx) : 0.f;
    red[t] = sum; __syncthreads();
    for (int o = 128; o > 0; o >>= 1) { if (t < o) red[t] += red[t + o]; __syncthreads(); }
    float s_total = red[0];
    float inv_s = (s_total > 0.f) ? 1.f / s_total : 0.f;
    for (int j = t; j < K_TOP; j += 256)
        decay[i * K_TOP + j] = (srow[j] > -5e8f) ? expf(srow[j] - mx) * inv_s : 0.f;
}

// ---------------- agg_d over j-major pair list, run-accumulated ----------------
__global__ __launch_bounds__(256) void k_aggd_p2(const unsigned int* plist, const int* npairs,
                                                 const float* xm, const float* dmat, const float* decay,
                                                 const float* mw1, const float* mb1,
                                                 const float* mw2, const float* mb2,
                                                 float* agg_m) {
    __shared__ float gbuf[4][G_DIM], tbuf[4][F_DIM];
    int t = threadIdx.x, wave = t >> 6, lane = t & 63;
    float w1r[G_DIM], w2r[F_DIM];
    #pragma unroll
    for (int g = 0; g < G_DIM; g++) w1r[g] = mw1[g * F_DIM + lane];
    #pragma unroll
    for (int k = 0; k < F_DIM; k++) w2r[k] = mw2[k * F_DIM + lane];
    float b1 = mb1[lane], b2v = mb2[lane];
    int n = npairs[0];
    int nchunks = (n + PCHUNK - 1) / PCHUNK;
    int wid = blockIdx.x * 4 + wave;
    int nw = gridDim.x * 4;
    for (int c = wid; c < nchunks; c += nw) {
        int p0 = c * PCHUNK;
        int p1 = min(p0 + PCHUNK, n);
        int curJ = -1;
        float acc = 0.f;
        for (int p = p0; p < p1; p++) {
            unsigned int key = plist[p];
            int j = key >> 9, i = key & (K_TOP - 1);
            int ij = i * K_TOP + j;
            float dd = dmat[ij];
            float dec = decay[ij];
            if (lane < G_DIM) { float u = dd - lane * STEP; gbuf[wave][lane] = expf(COEFF * u * u) * dec; }
            float tv = b1;
            #pragma unroll
            for (int g = 0; g < G_DIM; g++) tv += gbuf[wave][g] * w1r[g];
            tv = ssp_f(tv);
            tbuf[wave][lane] = tv;
            float w = b2v;
            #pragma unroll
            for (int k = 0; k < F_DIM; k++) w += tbuf[wave][k] * w2r[k];
            float contrib = xm[i * F_DIM + lane] * w * ccut_f(dd);
            if (j != curJ) {
                if (curJ >= 0) atomicAdd(&agg_m[curJ * F_DIM + lane], acc);
                acc = 0.f;
                curJ = j;
            }
            acc += contrib;
        }
        if (curJ >= 0) atomicAdd(&agg_m[curJ * F_DIM + lane], acc);
    }
}

// ---------------- valid-edge filter over compacted edge list ----------------
__global__ __launch_bounds__(256) void k_aggs_p(const int* velist, const int* nve,
                                                const float* pos_m, const int* src, const int* dst,
                                                const int* invg, const float* xm,
                                                const float* mw1, const float* mb1,
                                                const float* mw2, const float* mb2,
                                                float* agg_m) {
    __shared__ float gbuf[4][G_DIM], tbuf[4][F_DIM];
    int t = threadIdx.x, wave = t >> 6, lane = t & 63;
    float w1r[G_DIM], w2r[F_DIM];
    #pragma unroll
    for (int g = 0; g < G_DIM; g++) w1r[g] = mw1[g * F_DIM + lane];
    #pragma unroll
    for (int k = 0; k < F_DIM; k++) w2r[k] = mw2[k * F_DIM + lane];
    float b1 = mb1[lane], b2v = mb2[lane];
    int n = nve[0];
    int wid = blockIdx.x * 4 + wave;
    int nw = gridDim.x * 4;
    for (int p = wid; p < n; p += nw) {
        int e = velist[p];
        int sm = invg[src[e]];
        int dm = invg[dst[e]];
        float dx = pos_m[sm * 3 + 0] - pos_m[dm * 3 + 0];
        float dy = pos_m[sm * 3 + 1] - pos_m[dm * 3 + 1];
        float dz = pos_m[sm * 3 + 2] - pos_m[dm * 3 + 2];
        float d = sqrtf(dx * dx + dy * dy + dz * dz + 1e-12f);
        if (lane < G_DIM) { float u = d - lane * STEP; gbuf[wave][lane] = expf(COEFF * u * u); }
        float tv = b1;
        #pragma unroll
        for (int g = 0; g < G_DIM; g++) tv += gbuf[wave][g] * w1r[g];
        tv = ssp_f(tv);
        tbuf[wave][lane] = tv;
        float w = b2v;
        #pragma unroll
        for (int k = 0; k < F_DIM; k++) w += tbuf[wave][k] * w2r[k];
        atomicAdd(&agg_m[dm * F_DIM + lane], xm[sm * F_DIM + lane] * w * ccut_f(d));
    }
}

// ---------------- blend ----------------
__global__ __launch_bounds__(256) void k_blend(const float* h_local, const float* h_hier,
                                               const int* is_m, const int* invg, const float* m,
                                               float* h_out) {
    int idx = blockIdx.x * 256 + threadIdx.x;
    int n = idx >> 7, c = idx & 127;
    float mm = m[n];
    float hh = is_m[n] ? h_hier[invg[n] * H_DIM + c] : 0.f;
    h_out[idx] = (1.f - mm) * h_local[idx] + mm * hh;
}

// ---------------- parallel segment-sum pooling ----------------
__global__ __launch_bounds__(256) void k_pool(const float* __restrict__ h, const int* __restrict__ batch,
                                              float* pooled) {
    int c = threadIdx.x & 127, a = threadIdx.x >> 7;
    int n0 = blockIdx.x * 64;
    float acc = 0.f;
    int cur = batch[n0 + a];
    for (int i = a; i < 64; i += 2) {
        int n = n0 + i;
        int b = batch[n];
        if (b != cur) { atomicAdd(&pooled[cur * H_DIM + c], acc); acc = 0.f; cur = b; }
        acc += h[n * H_DIM + c];
    }
    atomicAdd(&pooled[cur * H_DIM + c], acc);
}

// ---------------- predict MLP ----------------
__global__ __launch_bounds__(128) void k_pred2(const float* pooled,
                                               const float* w1, const float* b1,
                                               const float* w2, const float* b2,
                                               void* outv, const int* flag) {
    __shared__ float c64[64];
    int b = blockIdx.x, t = threadIdx.x;
    if (t < 64) {
        float v = b1[t];
        for (int k = 0; k < H_DIM; k++) v += pooled[b * H_DIM + k] * w1[k * 64 + t];
        c64[t] = v * sigm_f(v);
    }
    __syncthreads();
    if (t == 0) {
        float o = b2[0];
        for (int k = 0; k < 64; k++) o += c64[k] * w2[k];
        if (flag[0]) ((float*)outv)[b] = o;
        else ((__hip_bfloat16*)outv)[b] = __float2bfloat16(o);
    }
}

extern "C" void kernel_launch(void* const* d_in, const int* in_sizes, int n_in,
                              void* d_out, int out_size, void* d_ws, size_t ws_size,
                              hipStream_t stream) {
    (void)n_in; (void)out_size; (void)ws_size;
    const int* atoms = (const int*)d_in[0];
    const int* src = (const int*)d_in[2];
    const int* dst = (const int*)d_in[3];
    const int* batch = (const int*)d_in[4];

    float* W = (float*)d_ws;
    int* dflag = (int*)W; W += 16;
    int* counters = (int*)W; W += 16;  // [0]=npairs, [1]=nve

    static const int fidx[25] = {1,5,6,7,8,9,10,11,12,13,14,15,16,17,18,19,20,21,22,23,24,25,26,27,28};
    float* fin[29];
    ConvArgs ca;
    float* convBase = W;
    int off = 0;
    for (int q = 0; q < 25; q++) {
        int i = fidx[q];
        ca.p[q] = d_in[i];
        ca.off[q] = off;
        fin[i] = convBase + off;
        off += in_sizes[i];
    }
    ca.off[25] = off;
    W += off;

    k_detect<<<1, 256, 0, stream>>>((const unsigned short*)d_in[5], in_sizes[5], dflag);
    k_convert_all<<<(off + 255) / 256, 256, 0, stream>>>(ca, convBase, dflag);

    const float* posf = fin[1];
    const float* embf = fin[5];

    float* h      = W; W += N_ATOMS * H_DIM;
    float* h_loc  = W; W += N_ATOMS * H_DIM;
    float* xbuf   = W; W += N_ATOMS * F_DIM;
    float* aggbuf = W; W += N_ATOMS * F_DIM;
    float* scores = W; W += N_ATOMS;
    float* mbuf   = W; W += N_ATOMS;
    float* h_m    = W; W += K_TOP * H_DIM;
    float* pos_m  = W; W += K_TOP * 3;
    float* xm     = W; W += K_TOP * F_DIM;
    float* qm     = W; W += K_TOP * S_DIM;
    float* km     = W; W += K_TOP * S_DIM;
    float* dmat   = W; W += K_TOP * K_TOP;
    float* decay  = W; W += K_TOP * K_TOP;
    float* sbuf   = W; W += K_TOP * K_TOP;
    float* hi     = W; W += K_TOP * H_DIM;
    float* hj     = W; W += K_TOP * H_DIM;
    float* agg_m  = W; W += K_TOP * F_DIM;
    float* h_hier = W; W += K_TOP * H_DIM;
    float* pooled = W; W += B_BATCH * H_DIM;
    int* rankb  = (int*)W; W += N_ATOMS;
    int* is_m   = (int*)W; W += N_ATOMS;
    int* invg   = (int*)W; W += N_ATOMS;
    int* midx   = (int*)W; W += K_TOP;
    unsigned int* plist = (unsigned int*)W; W += K_TOP * K_TOP;
    int* velist = (int*)W; W += E_EDGES;
    int* esorted = (int*)W; W += E_EDGES;
    int* ehist  = (int*)W; W += N_ATOMS;
    int* ebase  = (int*)W; W += N_ATOMS;
    int* ecur   = (int*)W; W += N_ATOMS;
    int* bcount = (int*)W; W += 1024;
    int* boffset = (int*)W; W += 1024;
    unsigned char* adj = (unsigned char*)W; W += (K_TOP * K_TOP) / 4;
    unsigned char* Av  = (unsigned char*)W; W += (K_TOP * K_TOP) / 4;

    // one-time: counting-sort edges by dst
    (void)hipMemsetAsync(ehist, 0, N_ATOMS * sizeof(int), stream);
    k_ehist<<<E_EDGES / 256, 256, 0, stream>>>(dst, ehist);
    k_escan<<<1, 1024, 0, stream>>>(ehist, ebase, ecur);
    k_escatter<<<E_EDGES / 256, 256, 0, stream>>>(dst, ecur, esorted);

    k_embed<<<(N_ATOMS * H_DIM) / 256, 256, 0, stream>>>(atoms, embf, h);

    for (int l = 0; l < L_LAYERS; l++) {
        const float* mw1 = fin[6]  + l * G_DIM * F_DIM;
        const float* mb1 = fin[7]  + l * F_DIM;
        const float* mw2 = fin[8]  + l * F_DIM * F_DIM;
        const float* mb2 = fin[9]  + l * F_DIM;
        const float* cf1 = fin[10] + l * H_DIM * F_DIM;
        const float* cf2w = fin[11] + l * F_DIM * H_DIM;
        const float* cf2b = fin[12] + l * H_DIM;
        const float* lw  = fin[13] + l * H_DIM * H_DIM;
        const float* lb  = fin[14] + l * H_DIM;
        const float* aw1 = fin[15] + l * (2 * H_DIM + G_DIM) * H_DIM;
        const float* ab1 = fin[16] + l * H_DIM;
        const float* aw2 = fin[17] + l * H_DIM;
        const float* ab2 = fin[18] + l;
        const float* msw1 = fin[19] + l * S_DIM * MH_DIM;
        const float* msb1 = fin[20] + l * MH_DIM;
        const float* msw2 = fin[21] + l * MH_DIM;
        const float* msb2 = fin[22] + l;
        const float* wq  = fin[23] + l * S_DIM * S_DIM;
        const float* wk  = fin[24] + l * S_DIM * S_DIM;

        k_x<<<N_ATOMS / 4, 256, 0, stream>>>(h, cf1, xbuf, N_ATOMS);
        (void)hipMemsetAsync(aggbuf, 0, N_ATOMS * F_DIM * sizeof(float), stream);
        k_edge_s<<<E_EDGES / (4 * EPW2), 256, 0, stream>>>(esorted, posf, src, dst, xbuf,
                                                           mw1, mb1, mw2, mb2, aggbuf);
        k_update<<<N_ATOMS / 4, 256, 0, stream>>>(aggbuf, h, cf2w, cf2b, lw, lb, h_loc, N_ATOMS);
        k_scores<<<N_ATOMS / 256, 256, 0, stream>>>(h_loc, msw1, msb1, msw2, msb2, scores);
        k_rank<<<N_ATOMS / 256, 256, 0, stream>>>(scores, rankb);
        k_select<<<1, 1024, 0, stream>>>(scores, rankb, is_m, invg, midx, mbuf);
        k_gather<<<(K_TOP * H_DIM) / 256, 256, 0, stream>>>(midx, h_loc, posf, h_m, pos_m);
        k_x<<<K_TOP / 4, 256, 0, stream>>>(h_m, cf1, xm, K_TOP);
        (void)hipMemsetAsync(adj, 0, K_TOP * K_TOP, stream);
        (void)hipMemsetAsync(counters, 0, 2 * sizeof(int), stream);
        k_adj<<<E_EDGES / 256, 256, 0, stream>>>(src, dst, is_m, invg, adj, velist, counters + 1);
        k_qk<<<(K_TOP * 32) / 256, 256, 0, stream>>>(h_m, wq, wk, qm, km);
        k_attn<<<K_TOP, 256, 0, stream>>>(qm, km, adj, Av);
        k_pcount<<<(K_TOP * K_TOP) / 256, 256, 0, stream>>>(Av, bcount);
        k_pscan<<<1, 1024, 0, stream>>>(bcount, boffset, counters);
        k_pscatter<<<(K_TOP * K_TOP) / 256, 256, 0, stream>>>(Av, boffset, plist);
        k_dmat<<<(K_TOP * K_TOP) / 256, 256, 0, stream>>>(pos_m, dmat);
        k_hij<<<(2 * K_TOP) / 4, 256, 0, stream>>>(h_m, aw1, hi, hj);
        k_score_p<<<1024, 256, 0, stream>>>(plist, counters, hi, hj, aw1, ab1, aw2, ab2, dmat, sbuf);
        k_decay<<<K_TOP, 256, 0, stream>>>(sbuf, Av, decay);
        (void)hipMemsetAsync(agg_m, 0, K_TOP * F_DIM * sizeof(float), stream);
        k_aggd_p2<<<1024, 256, 0, stream>>>(plist, counters, xm, dmat, decay, mw1, mb1, mw2, mb2, agg_m);
        k_aggs_p<<<256, 256, 0, stream>>>(velist, counters + 1, pos_m, src, dst, invg, xm,
                                          mw1, mb1, mw2, mb2, agg_m);
        k_update<<<K_TOP / 4, 256, 0, stream>>>(agg_m, h_m, cf2w, cf2b, lw, lb, h_hier, K_TOP);
        k_blend<<<(N_ATOMS * H_DIM) / 256, 256, 0, stream>>>(h_loc, h_hier, is_m, invg, mbuf, h);
    }

    (void)hipMemsetAsync(pooled, 0, B_BATCH * H_DIM * sizeof(float), stream);
    k_pool<<<N_ATOMS / 64, 256, 0, stream>>>(h, batch, pooled);
    k_pred2<<<B_BATCH, 128, 0, stream>>>(pooled, fin[25], fin[26], fin[27], fin[28], d_out, dflag);
}

// Round 9
// 764.016 us; speedup vs baseline: 1.3016x; 1.0385x over previous
//
#include <hip/hip_runtime.h>
#include <hip/hip_bf16.h>
#include <math.h>

#define N_ATOMS 2048
#define E_EDGES 65536
#define B_BATCH 8
#define H_DIM 128
#define G_DIM 50
#define F_DIM 64
#define S_DIM 16
#define MH_DIM 32
#define K_TOP 512
#define L_LAYERS 2
#define EPW2 16         // sorted edges per wave in k_edge_s
#define PCHUNK 32       // pairs per wave-chunk in k_aggd_p2
#define GPAD 52         // gbuf padded to 13 float4

static constexpr float STEP   = 10.0f / 49.0f;          // OFFSET spacing
static constexpr float COEFF  = -12.005f;               // -0.5/STEP^2
static constexpr float PI10   = 0.31415926535897931f;   // pi/CUTOFF
static constexpr float LN2    = 0.69314718055994531f;
static constexpr float LAMBDA = 0.002f;

#define DEV static __device__ __forceinline__

DEV float ssp_f(float x) { return fmaxf(x, 0.f) + log1pf(expf(-fabsf(x))) - LN2; }
DEV float ccut_f(float d) { return 0.5f * (cosf(d * PI10) + 1.f); }
DEV float sigm_f(float x) { return 1.f / (1.f + expf(-x)); }

// ---------------- dtype detect ----------------
__global__ __launch_bounds__(256) void k_detect(const unsigned short* raw, int n, int* flag) {
    __shared__ int any;
    if (threadIdx.x == 0) any = 0;
    __syncthreads();
    for (int i = threadIdx.x; i < n; i += 256) {
        unsigned int bits = ((unsigned int)raw[i]) << 16;
        float f = __uint_as_float(bits);
        if (!(fabsf(f) <= 1e10f)) any = 1;
    }
    __syncthreads();
    if (threadIdx.x == 0) flag[0] = any;
}

// ---------------- fused convert ----------------
struct ConvArgs {
    const void* p[25];
    int off[26];
};

__global__ __launch_bounds__(256) void k_convert_all(ConvArgs a, float* dst, const int* flag) {
    int i = blockIdx.x * 256 + threadIdx.x;
    int total = a.off[25];
    if (i >= total) return;
    int seg = 0;
    while (i >= a.off[seg + 1]) seg++;
    int k = i - a.off[seg];
    if (flag[0]) {
        dst[i] = ((const float*)a.p[seg])[k];
    } else {
        unsigned int bits = ((unsigned int)((const unsigned short*)a.p[seg])[k]) << 16;
        dst[i] = __uint_as_float(bits);
    }
}

// ---------------- edge counting-sort by dst ----------------
__global__ __launch_bounds__(256) void k_ehist(const int* dst, int* hist) {
    int e = blockIdx.x * 256 + threadIdx.x;
    atomicAdd(&hist[dst[e]], 1);
}

__global__ __launch_bounds__(1024) void k_escan(const int* hist, int* ebase, int* ecur) {
    __shared__ int bufA[N_ATOMS], bufB[N_ATOMS];
    int t = threadIdx.x;
    for (int i = t; i < N_ATOMS; i += 1024) bufA[i] = hist[i];
    __syncthreads();
    int* in = bufA;
    int* out = bufB;
    for (int d = 1; d < N_ATOMS; d <<= 1) {
        for (int i = t; i < N_ATOMS; i += 1024) out[i] = in[i] + (i >= d ? in[i - d] : 0);
        __syncthreads();
        int* tmp = in; in = out; out = tmp;
    }
    for (int i = t; i < N_ATOMS; i += 1024) {
        int ex = in[i] - hist[i];
        ebase[i] = ex;
        ecur[i] = ex;
    }
}

__global__ __launch_bounds__(256) void k_escatter(const int* dst, int* ecur, int* esorted) {
    int e = blockIdx.x * 256 + threadIdx.x;
    int pos = atomicAdd(&ecur[dst[e]], 1);
    esorted[pos] = e;
}

// ---------------- embedding ----------------
__global__ __launch_bounds__(256) void k_embed(const int* atoms, const float* emb, float* h) {
    int i = blockIdx.x * 256 + threadIdx.x;
    int n = i >> 7, c = i & 127;
    h[i] = emb[atoms[n] * H_DIM + c];
}

// ---------------- x = h @ cf1 ----------------
__global__ __launch_bounds__(256) void k_x(const float* __restrict__ h, const float* __restrict__ cf1,
                                           float* __restrict__ x, int M) {
    int wave = threadIdx.x >> 6, lane = threadIdx.x & 63;
    int n = blockIdx.x * 4 + wave;
    if (n >= M) return;
    float acc = 0.f;
    for (int k = 0; k < H_DIM; k++) acc += h[n * H_DIM + k] * cf1[k * F_DIM + lane];
    x[n * F_DIM + lane] = acc;
}

// ---------------- edge filter over dst-sorted edges, b128 broadcasts ----------------
__global__ __launch_bounds__(256) void k_edge_s(const int* esorted, const float* pos,
                                                const int* src, const int* dst, const float* x,
                                                const float* mw1, const float* mb1,
                                                const float* mw2, const float* mb2,
                                                float* agg) {
    __shared__ float gbuf[4][GPAD], tbuf[4][F_DIM];
    int t = threadIdx.x, wave = t >> 6, lane = t & 63;
    float w1r[GPAD], w2r[F_DIM];
    #pragma unroll
    for (int g = 0; g < G_DIM; g++) w1r[g] = mw1[g * F_DIM + lane];
    w1r[50] = 0.f; w1r[51] = 0.f;
    #pragma unroll
    for (int k = 0; k < F_DIM; k++) w2r[k] = mw2[k * F_DIM + lane];
    float b1 = mb1[lane], b2v = mb2[lane];
    if (lane >= G_DIM && lane < GPAD) gbuf[wave][lane] = 0.f;
    int p0 = (blockIdx.x * 4 + wave) * EPW2;
    int curDst = -1;
    float acc = 0.f;
    for (int ee = 0; ee < EPW2; ee++) {
        int e = esorted[p0 + ee];
        int sI = src[e], dI = dst[e];
        float dx = pos[sI * 3 + 0] - pos[dI * 3 + 0];
        float dy = pos[sI * 3 + 1] - pos[dI * 3 + 1];
        float dz = pos[sI * 3 + 2] - pos[dI * 3 + 2];
        float d = sqrtf(dx * dx + dy * dy + dz * dz + 1e-12f);
        if (lane < G_DIM) { float u = d - lane * STEP; gbuf[wave][lane] = expf(COEFF * u * u); }
        float tv = b1;
        const float4* g4 = (const float4*)gbuf[wave];
        #pragma unroll
        for (int gg = 0; gg < 13; gg++) {
            float4 gv = g4[gg];
            tv += gv.x * w1r[4 * gg + 0];
            tv += gv.y * w1r[4 * gg + 1];
            tv += gv.z * w1r[4 * gg + 2];
            tv += gv.w * w1r[4 * gg + 3];
        }
        tv = ssp_f(tv);
        tbuf[wave][lane] = tv;
        float w = b2v;
        const float4* t4v = (const float4*)tbuf[wave];
        #pragma unroll
        for (int kk = 0; kk < 16; kk++) {
            float4 tq = t4v[kk];
            w += tq.x * w2r[4 * kk + 0];
            w += tq.y * w2r[4 * kk + 1];
            w += tq.z * w2r[4 * kk + 2];
            w += tq.w * w2r[4 * kk + 3];
        }
        w *= ccut_f(d);
        float contrib = x[sI * F_DIM + lane] * w;
        if (dI != curDst) {
            if (curDst >= 0) atomicAdd(&agg[curDst * F_DIM + lane], acc);
            acc = 0.f;
            curDst = dI;
        }
        acc += contrib;
    }
    if (curDst >= 0) atomicAdd(&agg[curDst * F_DIM + lane], acc);
}

// ---------------- out = base + ssp(agg@cf2w + cf2b) @ lw + lb ----------------
__global__ __launch_bounds__(256) void k_update(const float* __restrict__ agg, const float* __restrict__ base,
                                                const float* cf2w, const float* cf2b,
                                                const float* lw, const float* lb,
                                                float* out, int M) {
    __shared__ float tbuf[4][H_DIM];
    int wave = threadIdx.x >> 6, lane = threadIdx.x & 63;
    int n = blockIdx.x * 4 + wave;
    float t0 = cf2b[lane], t1 = cf2b[lane + 64];
    if (n < M) {
        for (int f = 0; f < F_DIM; f++) {
            float a = agg[n * F_DIM + f];
            t0 += a * cf2w[f * H_DIM + lane];
            t1 += a * cf2w[f * H_DIM + lane + 64];
        }
    }
    tbuf[wave][lane] = ssp_f(t0);
    tbuf[wave][lane + 64] = ssp_f(t1);
    __syncthreads();
    if (n < M) {
        float o0 = lb[lane], o1 = lb[lane + 64];
        const float4* t4v = (const float4*)tbuf[wave];
        #pragma unroll
        for (int kk = 0; kk < 32; kk++) {
            float4 tq = t4v[kk];
            int k4 = kk * 4;
            o0 += tq.x * lw[(k4 + 0) * H_DIM + lane];
            o1 += tq.x * lw[(k4 + 0) * H_DIM + lane + 64];
            o0 += tq.y * lw[(k4 + 1) * H_DIM + lane];
            o1 += tq.y * lw[(k4 + 1) * H_DIM + lane + 64];
            o0 += tq.z * lw[(k4 + 2) * H_DIM + lane];
            o1 += tq.z * lw[(k4 + 2) * H_DIM + lane + 64];
            o0 += tq.w * lw[(k4 + 3) * H_DIM + lane];
            o1 += tq.w * lw[(k4 + 3) * H_DIM + lane + 64];
        }
        out[n * H_DIM + lane]      = base[n * H_DIM + lane] + o0;
        out[n * H_DIM + lane + 64] = base[n * H_DIM + lane + 64] + o1;
    }
}

// ---------------- node scores ----------------
__global__ __launch_bounds__(256) void k_scores(const float* h_local,
                                                const float* msw1, const float* msb1,
                                                const float* msw2, const float* msb2,
                                                float* scores) {
    int n = blockIdx.x * 256 + threadIdx.x;
    if (n >= N_ATOMS) return;
    float hs[S_DIM];
    for (int s = 0; s < S_DIM; s++) hs[s] = h_local[n * H_DIM + s];
    float sc = msb2[0];
    for (int j = 0; j < MH_DIM; j++) {
        float v = msb1[j];
        for (int s = 0; s < S_DIM; s++) v += hs[s] * msw1[s * MH_DIM + j];
        sc += fmaxf(v, 0.f) * msw2[j];
    }
    scores[n] = sc;
}

// ---------------- exact rank ----------------
__global__ __launch_bounds__(256) void k_rank(const float* scores, int* rank) {
    __shared__ float s[N_ATOMS];
    for (int i = threadIdx.x; i < N_ATOMS; i += 256) s[i] = scores[i];
    __syncthreads();
    int i = blockIdx.x * 256 + threadIdx.x;
    float si = s[i];
    int r = 0;
    for (int j = 0; j < N_ATOMS; j++) {
        float sj = s[j];
        r += (sj > si) || (sj == si && j < i);
    }
    rank[i] = r;
}

// ---------------- selection, prefix, midx, m ----------------
__global__ __launch_bounds__(1024) void k_select(const float* scores, const int* rank,
                                                 int* is_m, int* invg, int* midx, float* m) {
    __shared__ int flag[N_ATOMS];
    __shared__ int bufA[N_ATOMS], bufB[N_ATOMS];
    __shared__ float kth;
    int t = threadIdx.x;
    for (int i = t; i < N_ATOMS; i += 1024) {
        int f = rank[i] < K_TOP;
        flag[i] = f;
        bufA[i] = f;
        if (rank[i] == K_TOP - 1) kth = scores[i];
    }
    __syncthreads();
    int* in = bufA;
    int* out = bufB;
    for (int d = 1; d < N_ATOMS; d <<= 1) {
        for (int i = t; i < N_ATOMS; i += 1024) out[i] = in[i] + (i >= d ? in[i - d] : 0);
        __syncthreads();
        int* tmp = in; in = out; out = tmp;
    }
    float kv = kth;
    for (int i = t; i < N_ATOMS; i += 1024) {
        int f = flag[i];
        int pos = in[i] - f;
        is_m[i] = f;
        invg[i] = f ? pos : 0;
        if (f) midx[pos] = i;
        m[i] = sigm_f(scores[i] - kv + 1e-6f);
    }
}

// ---------------- gather h_m / pos_m ----------------
__global__ __launch_bounds__(256) void k_gather(const int* midx, const float* h_local,
                                                const float* pos, float* h_m, float* pos_m) {
    int i = blockIdx.x * 256 + threadIdx.x;
    int k = i >> 7, c = i & 127;
    int n = midx[k];
    h_m[i] = h_local[n * H_DIM + c];
    if (c < 3) pos_m[k * 3 + c] = pos[n * 3 + c];
}

// ---------------- adjacency + valid-edge list ----------------
__global__ __launch_bounds__(256) void k_adj(const int* src, const int* dst, const int* is_m,
                                             const int* invg, unsigned char* adj,
                                             int* velist, int* nve) {
    int e = blockIdx.x * 256 + threadIdx.x;
    int s = src[e], d = dst[e];
    bool valid = is_m[s] && is_m[d];
    if (valid) adj[invg[s] * K_TOP + invg[d]] = 1;
    unsigned long long mask = __ballot(valid);
    int lane = threadIdx.x & 63;
    int cnt = __popcll(mask);
    int base = 0;
    if (lane == 0 && cnt) base = atomicAdd(nve, cnt);
    base = __shfl(base, 0);
    if (valid) velist[base + __popcll(mask & ((1ull << lane) - 1))] = e;
}

// ---------------- q/k projections ----------------
__global__ __launch_bounds__(256) void k_qk(const float* h_m, const float* wq,
                                            const float* wk, float* qm, float* km) {
    int gid = blockIdx.x * 256 + threadIdx.x;
    int r = gid >> 5, t = gid & 31;
    const float* w = (t < 16) ? wq : wk;
    int c = t & 15;
    float acc = 0.f;
    for (int s = 0; s < S_DIM; s++) acc += h_m[r * H_DIM + s] * w[s * S_DIM + c];
    if (t < 16) qm[r * S_DIM + c] = acc; else km[r * S_DIM + c] = acc;
}

// ---------------- attention softmax -> Av mask ----------------
__global__ __launch_bounds__(256) void k_attn(const float* qm, const float* km,
                                              const unsigned char* adj, unsigned char* Av) {
    __shared__ float lrow[K_TOP];
    __shared__ float red[256];
    int i = blockIdx.x, t = threadIdx.x;
    float q[S_DIM];
    for (int s = 0; s < S_DIM; s++) q[s] = qm[i * S_DIM + s];
    for (int j = t; j < K_TOP; j += 256) {
        float acc = 0.f;
        for (int s = 0; s < S_DIM; s++) acc += q[s] * km[j * S_DIM + s];
        lrow[j] = acc * 0.25f;
    }
    __syncthreads();
    float mx = -1e30f;
    for (int j = t; j < K_TOP; j += 256) mx = fmaxf(mx, lrow[j]);
    red[t] = mx; __syncthreads();
    for (int o = 128; o > 0; o >>= 1) { if (t < o) red[t] = fmaxf(red[t], red[t + o]); __syncthreads(); }
    mx = red[0]; __syncthreads();
    float sum = 0.f;
    for (int j = t; j < K_TOP; j += 256) sum += expf(lrow[j] - mx);
    red[t] = sum; __syncthreads();
    for (int o = 128; o > 0; o >>= 1) { if (t < o) red[t] += red[t + o]; __syncthreads(); }
    float inv_s = 1.f / red[0];
    for (int j = t; j < K_TOP; j += 256) {
        float a = expf(lrow[j] - mx) * inv_s;
        Av[i * K_TOP + j] = (a > LAMBDA) && (!adj[i * K_TOP + j]) && (i != j);
    }
}

// ---------------- deterministic j-major pair compaction ----------------
__global__ __launch_bounds__(256) void k_pcount(const unsigned char* Av, int* bcount) {
    __shared__ int wsum[4];
    int idx = blockIdx.x * 256 + threadIdx.x;
    int j = idx >> 9, i = idx & (K_TOP - 1);
    bool act = Av[i * K_TOP + j] != 0;
    unsigned long long mask = __ballot(act);
    int lane = threadIdx.x & 63, wave = threadIdx.x >> 6;
    if (lane == 0) wsum[wave] = __popcll(mask);
    __syncthreads();
    if (threadIdx.x == 0) bcount[blockIdx.x] = wsum[0] + wsum[1] + wsum[2] + wsum[3];
}

__global__ __launch_bounds__(1024) void k_pscan(const int* bcount, int* boffset, int* total) {
    __shared__ int bufA[1024], bufB[1024];
    int t = threadIdx.x;
    bufA[t] = bcount[t];
    __syncthreads();
    int* in = bufA;
    int* out = bufB;
    for (int d = 1; d < 1024; d <<= 1) {
        out[t] = in[t] + (t >= d ? in[t - d] : 0);
        __syncthreads();
        int* tmp = in; in = out; out = tmp;
    }
    boffset[t] = in[t] - bcount[t];
    if (t == 1023) total[0] = in[1023];
}

__global__ __launch_bounds__(256) void k_pscatter(const unsigned char* Av, const int* boffset,
                                                  unsigned int* plist) {
    __shared__ int wsum[4], woff[4];
    int idx = blockIdx.x * 256 + threadIdx.x;
    int j = idx >> 9, i = idx & (K_TOP - 1);
    bool act = Av[i * K_TOP + j] != 0;
    unsigned long long mask = __ballot(act);
    int lane = threadIdx.x & 63, wave = threadIdx.x >> 6;
    if (lane == 0) wsum[wave] = __popcll(mask);
    __syncthreads();
    if (threadIdx.x == 0) {
        int s = 0;
        for (int w = 0; w < 4; w++) { woff[w] = s; s += wsum[w]; }
    }
    __syncthreads();
    if (act) {
        int pos = boffset[blockIdx.x] + woff[wave] + __popcll(mask & ((1ull << lane) - 1));
        plist[pos] = ((unsigned int)j << 9) | (unsigned int)i;
    }
}

// ---------------- pairwise distances ----------------
__global__ __launch_bounds__(256) void k_dmat(const float* pos_m, float* dmat) {
    int idx = blockIdx.x * 256 + threadIdx.x;
    int i = idx >> 9, j = idx & (K_TOP - 1);
    float dx = pos_m[i * 3 + 0] - pos_m[j * 3 + 0];
    float dy = pos_m[i * 3 + 1] - pos_m[j * 3 + 1];
    float dz = pos_m[i * 3 + 2] - pos_m[j * 3 + 2];
    dmat[idx] = sqrtf(dx * dx + dy * dy + dz * dz + 1e-12f);
}

// ---------------- hi = h_m@Wi, hj = h_m@Wj ----------------
__global__ __launch_bounds__(256) void k_hij(const float* h_m, const float* aw1,
                                             float* hi, float* hj) {
    int wave = threadIdx.x >> 6, lane = threadIdx.x & 63;
    int idx = blockIdx.x * 4 + wave;
    int which = idx >> 9;
    int r = idx & (K_TOP - 1);
    const float* W = aw1 + which * H_DIM * H_DIM;
    float o0 = 0.f, o1 = 0.f;
    for (int k = 0; k < H_DIM; k++) {
        float hv = h_m[r * H_DIM + k];
        o0 += hv * W[k * H_DIM + lane];
        o1 += hv * W[k * H_DIM + lane + 64];
    }
    float* out = which ? hj : hi;
    out[r * H_DIM + lane] = o0;
    out[r * H_DIM + lane + 64] = o1;
}

// ---------------- per-pair attention scores, b128 broadcasts ----------------
__global__ __launch_bounds__(256) void k_score_p(const unsigned int* plist, const int* npairs,
                                                 const float* hi, const float* hj,
                                                 const float* aw1, const float* ab1,
                                                 const float* aw2, const float* ab2,
                                                 const float* dmat, float* sbuf) {
    __shared__ float gbuf[4][GPAD];
    int t = threadIdx.x, wave = t >> 6, lane = t & 63;
    const float* wd = aw1 + 2 * H_DIM * H_DIM;
    float wdr0[GPAD], wdr1[GPAD];
    #pragma unroll
    for (int g = 0; g < G_DIM; g++) {
        wdr0[g] = wd[g * H_DIM + lane];
        wdr1[g] = wd[g * H_DIM + lane + 64];
    }
    wdr0[50] = 0.f; wdr0[51] = 0.f;
    wdr1[50] = 0.f; wdr1[51] = 0.f;
    float ab0 = ab1[lane], ab1v = ab1[lane + 64];
    float aw0 = aw2[lane], aw1v = aw2[lane + 64];
    float b2 = ab2[0];
    if (lane >= G_DIM && lane < GPAD) gbuf[wave][lane] = 0.f;
    int n = npairs[0];
    int wid = blockIdx.x * 4 + wave;
    int nw = gridDim.x * 4;
    for (int p = wid; p < n; p += nw) {
        unsigned int key = plist[p];
        int j = key >> 9, i = key & (K_TOP - 1);
        int ij = i * K_TOP + j;
        float dd = dmat[ij];
        if (lane < G_DIM) { float u = dd - lane * STEP; gbuf[wave][lane] = expf(COEFF * u * u); }
        float v0 = hi[i * H_DIM + lane] + hj[j * H_DIM + lane] + ab0;
        float v1 = hi[i * H_DIM + lane + 64] + hj[j * H_DIM + lane + 64] + ab1v;
        const float4* g4 = (const float4*)gbuf[wave];
        #pragma unroll
        for (int gg = 0; gg < 13; gg++) {
            float4 gv = g4[gg];
            v0 += gv.x * wdr0[4 * gg + 0]; v1 += gv.x * wdr1[4 * gg + 0];
            v0 += gv.y * wdr0[4 * gg + 1]; v1 += gv.y * wdr1[4 * gg + 1];
            v0 += gv.z * wdr0[4 * gg + 2]; v1 += gv.z * wdr1[4 * gg + 2];
            v0 += gv.w * wdr0[4 * gg + 3]; v1 += gv.w * wdr1[4 * gg + 3];
        }
        float pv = fmaxf(v0, 0.f) * aw0 + fmaxf(v1, 0.f) * aw1v;
        for (int o = 1; o < 64; o <<= 1) pv += __shfl_xor(pv, o);
        if (lane == 0) sbuf[ij] = pv + b2;
    }
}

// ---------------- row softmax (Av-guarded) -> decay ----------------
__global__ __launch_bounds__(256) void k_decay(const float* sbuf, const unsigned char* Av, float* decay) {
    __shared__ float srow[K_TOP];
    __shared__ float red[256];
    int i = blockIdx.x, t = threadIdx.x;
    for (int j = t; j < K_TOP; j += 256)
        srow[j] = Av[i * K_TOP + j] ? sbuf[i * K_TOP + j] : -1e9f;
    __syncthreads();
    float mx = -1e30f;
    for (int j = t; j < K_TOP; j += 256) mx = fmaxf(mx, srow[j]);
    red[t] = mx; __syncthreads();
    for (int o = 128; o > 0; o >>= 1) { if (t < o) red[t] = fmaxf(red[t], red[t + o]); __syncthreads(); }
    mx = red[0]; __syncthreads();
    float sum = 0.f;
    for (int j = t; j < K_TOP; j += 256) sum += (srow[j] > -5e8f) ? expf(srow[j] - mx) : 0.f;
    red[t] = sum; __syncthreads();
    for (int o = 128; o > 0; o >>= 1) { if (t < o) red[t] += red[t + o]; __syncthreads(); }
    float s_total = red[0];
    float inv_s = (s_total > 0.f) ? 1.f / s_total : 0.f;
    for (int j = t; j < K_TOP; j += 256)
        decay[i * K_TOP + j] = (srow[j] > -5e8f) ? expf(srow[j] - mx) * inv_s : 0.f;
}

// ---------------- agg_d over j-major pair list, b128 broadcasts ----------------
__global__ __launch_bounds__(256) void k_aggd_p2(const unsigned int* plist, const int* npairs,
                                                 const float* xm, const float* dmat, const float* decay,
                                                 const float* mw1, const float* mb1,
                                                 const float* mw2, const float* mb2,
                                                 float* agg_m) {
    __shared__ float gbuf[4][GPAD], tbuf[4][F_DIM];
    int t = threadIdx.x, wave = t >> 6, lane = t & 63;
    float w1r[GPAD], w2r[F_DIM];
    #pragma unroll
    for (int g = 0; g < G_DIM; g++) w1r[g] = mw1[g * F_DIM + lane];
    w1r[50] = 0.f; w1r[51] = 0.f;
    #pragma unroll
    for (int k = 0; k < F_DIM; k++) w2r[k] = mw2[k * F_DIM + lane];
    float b1 = mb1[lane], b2v = mb2[lane];
    if (lane >= G_DIM && lane < GPAD) gbuf[wave][lane] = 0.f;
    int n = npairs[0];
    int nchunks = (n + PCHUNK - 1) / PCHUNK;
    int wid = blockIdx.x * 4 + wave;
    int nw = gridDim.x * 4;
    for (int c = wid; c < nchunks; c += nw) {
        int p0 = c * PCHUNK;
        int p1 = min(p0 + PCHUNK, n);
        int curJ = -1;
        float acc = 0.f;
        for (int p = p0; p < p1; p++) {
            unsigned int key = plist[p];
            int j = key >> 9, i = key & (K_TOP - 1);
            int ij = i * K_TOP + j;
            float dd = dmat[ij];
            float dec = decay[ij];
            if (lane < G_DIM) { float u = dd - lane * STEP; gbuf[wave][lane] = expf(COEFF * u * u) * dec; }
            float tv = b1;
            const float4* g4 = (const float4*)gbuf[wave];
            #pragma unroll
            for (int gg = 0; gg < 13; gg++) {
                float4 gv = g4[gg];
                tv += gv.x * w1r[4 * gg + 0];
                tv += gv.y * w1r[4 * gg + 1];
                tv += gv.z * w1r[4 * gg + 2];
                tv += gv.w * w1r[4 * gg + 3];
            }
            tv = ssp_f(tv);
            tbuf[wave][lane] = tv;
            float w = b2v;
            const float4* t4v = (const float4*)tbuf[wave];
            #pragma unroll
            for (int kk = 0; kk < 16; kk++) {
                float4 tq = t4v[kk];
                w += tq.x * w2r[4 * kk + 0];
                w += tq.y * w2r[4 * kk + 1];
                w += tq.z * w2r[4 * kk + 2];
                w += tq.w * w2r[4 * kk + 3];
            }
            float contrib = xm[i * F_DIM + lane] * w * ccut_f(dd);
            if (j != curJ) {
                if (curJ >= 0) atomicAdd(&agg_m[curJ * F_DIM + lane], acc);
                acc = 0.f;
                curJ = j;
            }
            acc += contrib;
        }
        if (curJ >= 0) atomicAdd(&agg_m[curJ * F_DIM + lane], acc);
    }
}

// ---------------- valid-edge filter over compacted list, b128 broadcasts ----------------
__global__ __launch_bounds__(256) void k_aggs_p(const int* velist, const int* nve,
                                                const float* pos_m, const int* src, const int* dst,
                                                const int* invg, const float* xm,
                                                const float* mw1, const float* mb1,
                                                const float* mw2, const float* mb2,
                                                float* agg_m) {
    __shared__ float gbuf[4][GPAD], tbuf[4][F_DIM];
    int t = threadIdx.x, wave = t >> 6, lane = t & 63;
    float w1r[GPAD], w2r[F_DIM];
    #pragma unroll
    for (int g = 0; g < G_DIM; g++) w1r[g] = mw1[g * F_DIM + lane];
    w1r[50] = 0.f; w1r[51] = 0.f;
    #pragma unroll
    for (int k = 0; k < F_DIM; k++) w2r[k] = mw2[k * F_DIM + lane];
    float b1 = mb1[lane], b2v = mb2[lane];
    if (lane >= G_DIM && lane < GPAD) gbuf[wave][lane] = 0.f;
    int n = nve[0];
    int wid = blockIdx.x * 4 + wave;
    int nw = gridDim.x * 4;
    for (int p = wid; p < n; p += nw) {
        int e = velist[p];
        int sm = invg[src[e]];
        int dm = invg[dst[e]];
        float dx = pos_m[sm * 3 + 0] - pos_m[dm * 3 + 0];
        float dy = pos_m[sm * 3 + 1] - pos_m[dm * 3 + 1];
        float dz = pos_m[sm * 3 + 2] - pos_m[dm * 3 + 2];
        float d = sqrtf(dx * dx + dy * dy + dz * dz + 1e-12f);
        if (lane < G_DIM) { float u = d - lane * STEP; gbuf[wave][lane] = expf(COEFF * u * u); }
        float tv = b1;
        const float4* g4 = (const float4*)gbuf[wave];
        #pragma unroll
        for (int gg = 0; gg < 13; gg++) {
            float4 gv = g4[gg];
            tv += gv.x * w1r[4 * gg + 0];
            tv += gv.y * w1r[4 * gg + 1];
            tv += gv.z * w1r[4 * gg + 2];
            tv += gv.w * w1r[4 * gg + 3];
        }
        tv = ssp_f(tv);
        tbuf[wave][lane] = tv;
        float w = b2v;
        const float4* t4v = (const float4*)tbuf[wave];
        #pragma unroll
        for (int kk = 0; kk < 16; kk++) {
            float4 tq = t4v[kk];
            w += tq.x * w2r[4 * kk + 0];
            w += tq.y * w2r[4 * kk + 1];
            w += tq.z * w2r[4 * kk + 2];
            w += tq.w * w2r[4 * kk + 3];
        }
        atomicAdd(&agg_m[dm * F_DIM + lane], xm[sm * F_DIM + lane] * w * ccut_f(d));
    }
}

// ---------------- blend ----------------
__global__ __launch_bounds__(256) void k_blend(const float* h_local, const float* h_hier,
                                               const int* is_m, const int* invg, const float* m,
                                               float* h_out) {
    int idx = blockIdx.x * 256 + threadIdx.x;
    int n = idx >> 7, c = idx & 127;
    float mm = m[n];
    float hh = is_m[n] ? h_hier[invg[n] * H_DIM + c] : 0.f;
    h_out[idx] = (1.f - mm) * h_local[idx] + mm * hh;
}

// ---------------- parallel segment-sum pooling ----------------
__global__ __launch_bounds__(256) void k_pool(const float* __restrict__ h, const int* __restrict__ batch,
                                              float* pooled) {
    int c = threadIdx.x & 127, a = threadIdx.x >> 7;
    int n0 = blockIdx.x * 64;
    float acc = 0.f;
    int cur = batch[n0 + a];
    for (int i = a; i < 64; i += 2) {
        int n = n0 + i;
        int b = batch[n];
        if (b != cur) { atomicAdd(&pooled[cur * H_DIM + c], acc); acc = 0.f; cur = b; }
        acc += h[n * H_DIM + c];
    }
    atomicAdd(&pooled[cur * H_DIM + c], acc);
}

// ---------------- predict MLP ----------------
__global__ __launch_bounds__(128) void k_pred2(const float* pooled,
                                               const float* w1, const float* b1,
                                               const float* w2, const float* b2,
                                               void* outv, const int* flag) {
    __shared__ float c64[64];
    int b = blockIdx.x, t = threadIdx.x;
    if (t < 64) {
        float v = b1[t];
        for (int k = 0; k < H_DIM; k++) v += pooled[b * H_DIM + k] * w1[k * 64 + t];
        c64[t] = v * sigm_f(v);
    }
    __syncthreads();
    if (t == 0) {
        float o = b2[0];
        for (int k = 0; k < 64; k++) o += c64[k] * w2[k];
        if (flag[0]) ((float*)outv)[b] = o;
        else ((__hip_bfloat16*)outv)[b] = __float2bfloat16(o);
    }
}

extern "C" void kernel_launch(void* const* d_in, const int* in_sizes, int n_in,
                              void* d_out, int out_size, void* d_ws, size_t ws_size,
                              hipStream_t stream) {
    (void)n_in; (void)out_size; (void)ws_size;
    const int* atoms = (const int*)d_in[0];
    const int* src = (const int*)d_in[2];
    const int* dst = (const int*)d_in[3];
    const int* batch = (const int*)d_in[4];

    float* W = (float*)d_ws;
    int* dflag = (int*)W; W += 16;
    int* counters = (int*)W; W += 16;  // [0]=npairs, [1]=nve

    static const int fidx[25] = {1,5,6,7,8,9,10,11,12,13,14,15,16,17,18,19,20,21,22,23,24,25,26,27,28};
    float* fin[29];
    ConvArgs ca;
    float* convBase = W;
    int off = 0;
    for (int q = 0; q < 25; q++) {
        int i = fidx[q];
        ca.p[q] = d_in[i];
        ca.off[q] = off;
        fin[i] = convBase + off;
        off += in_sizes[i];
    }
    ca.off[25] = off;
    W += off;

    k_detect<<<1, 256, 0, stream>>>((const unsigned short*)d_in[5], in_sizes[5], dflag);
    k_convert_all<<<(off + 255) / 256, 256, 0, stream>>>(ca, convBase, dflag);

    const float* posf = fin[1];
    const float* embf = fin[5];

    float* h      = W; W += N_ATOMS * H_DIM;
    float* h_loc  = W; W += N_ATOMS * H_DIM;
    float* xbuf   = W; W += N_ATOMS * F_DIM;
    float* aggbuf = W; W += N_ATOMS * F_DIM;
    float* scores = W; W += N_ATOMS;
    float* mbuf   = W; W += N_ATOMS;
    float* h_m    = W; W += K_TOP * H_DIM;
    float* pos_m  = W; W += K_TOP * 3;
    float* xm     = W; W += K_TOP * F_DIM;
    float* qm     = W; W += K_TOP * S_DIM;
    float* km     = W; W += K_TOP * S_DIM;
    float* dmat   = W; W += K_TOP * K_TOP;
    float* decay  = W; W += K_TOP * K_TOP;
    float* sbuf   = W; W += K_TOP * K_TOP;
    float* hi     = W; W += K_TOP * H_DIM;
    float* hj     = W; W += K_TOP * H_DIM;
    float* agg_m  = W; W += K_TOP * F_DIM;
    float* h_hier = W; W += K_TOP * H_DIM;
    float* pooled = W; W += B_BATCH * H_DIM;
    int* rankb  = (int*)W; W += N_ATOMS;
    int* is_m   = (int*)W; W += N_ATOMS;
    int* invg   = (int*)W; W += N_ATOMS;
    int* midx   = (int*)W; W += K_TOP;
    unsigned int* plist = (unsigned int*)W; W += K_TOP * K_TOP;
    int* velist = (int*)W; W += E_EDGES;
    int* esorted = (int*)W; W += E_EDGES;
    int* ehist  = (int*)W; W += N_ATOMS;
    int* ebase  = (int*)W; W += N_ATOMS;
    int* ecur   = (int*)W; W += N_ATOMS;
    int* bcount = (int*)W; W += 1024;
    int* boffset = (int*)W; W += 1024;
    unsigned char* adj = (unsigned char*)W; W += (K_TOP * K_TOP) / 4;
    unsigned char* Av  = (unsigned char*)W; W += (K_TOP * K_TOP) / 4;

    // one-time: counting-sort edges by dst
    (void)hipMemsetAsync(ehist, 0, N_ATOMS * sizeof(int), stream);
    k_ehist<<<E_EDGES / 256, 256, 0, stream>>>(dst, ehist);
    k_escan<<<1, 1024, 0, stream>>>(ehist, ebase, ecur);
    k_escatter<<<E_EDGES / 256, 256, 0, stream>>>(dst, ecur, esorted);

    k_embed<<<(N_ATOMS * H_DIM) / 256, 256, 0, stream>>>(atoms, embf, h);

    for (int l = 0; l < L_LAYERS; l++) {
        const float* mw1 = fin[6]  + l * G_DIM * F_DIM;
        const float* mb1 = fin[7]  + l * F_DIM;
        const float* mw2 = fin[8]  + l * F_DIM * F_DIM;
        const float* mb2 = fin[9]  + l * F_DIM;
        const float* cf1 = fin[10] + l * H_DIM * F_DIM;
        const float* cf2w = fin[11] + l * F_DIM * H_DIM;
        const float* cf2b = fin[12] + l * H_DIM;
        const float* lw  = fin[13] + l * H_DIM * H_DIM;
        const float* lb  = fin[14] + l * H_DIM;
        const float* aw1 = fin[15] + l * (2 * H_DIM + G_DIM) * H_DIM;
        const float* ab1 = fin[16] + l * H_DIM;
        const float* aw2 = fin[17] + l * H_DIM;
        const float* ab2 = fin[18] + l;
        const float* msw1 = fin[19] + l * S_DIM * MH_DIM;
        const float* msb1 = fin[20] + l * MH_DIM;
        const float* msw2 = fin[21] + l * MH_DIM;
        const float* msb2 = fin[22] + l;
        const float* wq  = fin[23] + l * S_DIM * S_DIM;
        const float* wk  = fin[24] + l * S_DIM * S_DIM;

        k_x<<<N_ATOMS / 4, 256, 0, stream>>>(h, cf1, xbuf, N_ATOMS);
        (void)hipMemsetAsync(aggbuf, 0, N_ATOMS * F_DIM * sizeof(float), stream);
        k_edge_s<<<E_EDGES / (4 * EPW2), 256, 0, stream>>>(esorted, posf, src, dst, xbuf,
                                                           mw1, mb1, mw2, mb2, aggbuf);
        k_update<<<N_ATOMS / 4, 256, 0, stream>>>(aggbuf, h, cf2w, cf2b, lw, lb, h_loc, N_ATOMS);
        k_scores<<<N_ATOMS / 256, 256, 0, stream>>>(h_loc, msw1, msb1, msw2, msb2, scores);
        k_rank<<<N_ATOMS / 256, 256, 0, stream>>>(scores, rankb);
        k_select<<<1, 1024, 0, stream>>>(scores, rankb, is_m, invg, midx, mbuf);
        k_gather<<<(K_TOP * H_DIM) / 256, 256, 0, stream>>>(midx, h_loc, posf, h_m, pos_m);
        k_x<<<K_TOP / 4, 256, 0, stream>>>(h_m, cf1, xm, K_TOP);
        (void)hipMemsetAsync(adj, 0, K_TOP * K_TOP, stream);
        (void)hipMemsetAsync(counters, 0, 2 * sizeof(int), stream);
        k_adj<<<E_EDGES / 256, 256, 0, stream>>>(src, dst, is_m, invg, adj, velist, counters + 1);
        k_qk<<<(K_TOP * 32) / 256, 256, 0, stream>>>(h_m, wq, wk, qm, km);
        k_attn<<<K_TOP, 256, 0, stream>>>(qm, km, adj, Av);
        k_pcount<<<(K_TOP * K_TOP) / 256, 256, 0, stream>>>(Av, bcount);
        k_pscan<<<1, 1024, 0, stream>>>(bcount, boffset, counters);
        k_pscatter<<<(K_TOP * K_TOP) / 256, 256, 0, stream>>>(Av, boffset, plist);
        k_dmat<<<(K_TOP * K_TOP) / 256, 256, 0, stream>>>(pos_m, dmat);
        k_hij<<<(2 * K_TOP) / 4, 256, 0, stream>>>(h_m, aw1, hi, hj);
        k_score_p<<<1024, 256, 0, stream>>>(plist, counters, hi, hj, aw1, ab1, aw2, ab2, dmat, sbuf);
        k_decay<<<K_TOP, 256, 0, stream>>>(sbuf, Av, decay);
        (void)hipMemsetAsync(agg_m, 0, K_TOP * F_DIM * sizeof(float), stream);
        k_aggd_p2<<<1024, 256, 0, stream>>>(plist, counters, xm, dmat, decay, mw1, mb1, mw2, mb2, agg_m);
        k_aggs_p<<<256, 256, 0, stream>>>(velist, counters + 1, pos_m, src, dst, invg, xm,
                                          mw1, mb1, mw2, mb2, agg_m);
        k_update<<<K_TOP / 4, 256, 0, stream>>>(agg_m, h_m, cf2w, cf2b, lw, lb, h_hier, K_TOP);
        k_blend<<<(N_ATOMS * H_DIM) / 256, 256, 0, stream>>>(h_loc, h_hier, is_m, invg, mbuf, h);
    }

    (void)hipMemsetAsync(pooled, 0, B_BATCH * H_DIM * sizeof(float), stream);
    k_pool<<<N_ATOMS / 64, 256, 0, stream>>>(h, batch, pooled);
    k_pred2<<<B_BATCH, 128, 0, stream>>>(pooled, fin[25], fin[26], fin[27], fin[28], d_out, dflag);
}